// Round 5
// baseline (545.911 us; speedup 1.0000x reference)
//
#include <hip/hip_runtime.h>
#include <math.h>

typedef unsigned short u16;
typedef unsigned int u32;
typedef __bf16 bf16x8 __attribute__((ext_vector_type(8)));
typedef float f32x4 __attribute__((ext_vector_type(4)));

#define NB 4
#define SS 2048
#define DD 768
#define HH 12
#define HD 64
#define ROWS (NB*SS)   // 8192

__device__ __forceinline__ u16 f2bf(float f) {
    union { float f; unsigned u; } v; v.f = f;
    unsigned r = v.u + 0x7fffu + ((v.u >> 16) & 1u);
    return (u16)(r >> 16);
}
__device__ __forceinline__ u32 fas(float f) { union { float f; u32 u; } v; v.f = f; return v.u; }

__device__ __forceinline__ void gl_lds16(const void* g, void* l) {
    __builtin_amdgcn_global_load_lds((__attribute__((address_space(1))) void*)(g),
                                     (__attribute__((address_space(3))) void*)(l),
                                     16, 0, 0);
}

// ---------------- fused prep: all f32->bf16 casts + mask bias ----------------
__global__ __launch_bounds__(256) void prep_kernel(
        const float* __restrict__ X, const float* __restrict__ Wq,
        const float* __restrict__ Wk, const float* __restrict__ Wv,
        const float* __restrict__ Wo, const float* __restrict__ W1,
        const float* __restrict__ W2, const int* __restrict__ mask,
        u16* __restrict__ Xb, u16* __restrict__ Wqkvb, u16* __restrict__ Wob,
        u16* __restrict__ W1b, u16* __restrict__ W2b, float* __restrict__ mb) {
    const int blk = blockIdx.x, tid = threadIdx.x;
    const float* src; u16* dst; int idx;
    if (blk < 6144)       { src = X;  dst = Xb;               idx = blk * 1024 + tid * 4; }
    else if (blk < 6720)  { src = Wq; dst = Wqkvb;            idx = (blk - 6144) * 1024 + tid * 4; }
    else if (blk < 7296)  { src = Wk; dst = Wqkvb + DD * DD;  idx = (blk - 6720) * 1024 + tid * 4; }
    else if (blk < 7872)  { src = Wv; dst = Wqkvb + 2*DD*DD;  idx = (blk - 7296) * 1024 + tid * 4; }
    else if (blk < 8448)  { src = Wo; dst = Wob;              idx = (blk - 7872) * 1024 + tid * 4; }
    else if (blk < 10752) { src = W1; dst = W1b;              idx = (blk - 8448) * 1024 + tid * 4; }
    else if (blk < 13056) { src = W2; dst = W2b;              idx = (blk - 10752) * 1024 + tid * 4; }
    else {
        int i = (blk - 13056) * 1024 + tid * 4;
        float4 o;
        o.x = mask[i]     == 0 ? -1e30f : 0.0f;
        o.y = mask[i + 1] == 0 ? -1e30f : 0.0f;
        o.z = mask[i + 2] == 0 ? -1e30f : 0.0f;
        o.w = mask[i + 3] == 0 ? -1e30f : 0.0f;
        *(float4*)&mb[i] = o;
        return;
    }
    float4 v = *(const float4*)&src[idx];
    ushort4 o;
    o.x = f2bf(v.x); o.y = f2bf(v.y); o.z = f2bf(v.z); o.w = f2bf(v.w);
    *(ushort4*)&dst[idx] = o;
}

// ---------------- GEMM: C[M,N] = A[M,K] (bf16) * B[N,K]^T (bf16) ----------------
// 128xBN tile, BK=64, 4 waves. Chunk-swizzled LDS (phys = c ^ (row&7)).
template <int EPI, int BN>
__global__ __launch_bounds__(256) void gemm_bt(const u16* __restrict__ A,
                                               const u16* __restrict__ B,
                                               int M, int N, int K,
                                               void* __restrict__ out,
                                               const void* __restrict__ aux,
                                               u16* __restrict__ Qb,
                                               u16* __restrict__ Kb,
                                               u16* __restrict__ Vb) {
    __shared__ __align__(16) u16 lA[128 * 64];
    __shared__ __align__(16) u16 lB[BN * 64];
    constexpr int MI = (BN == 128) ? 4 : 2;
    const int tid = threadIdx.x;
    const int lane = tid & 63, wave = tid >> 6;
    const int quad = lane >> 4, lc = lane & 15;
    const int m0 = blockIdx.y * 128, n0 = blockIdx.x * BN;
    const int wrow = (BN == 128) ? (wave >> 1) * 64 : wave * 32;
    const int wcol = (BN == 128) ? (wave & 1) * 64 : 0;
    const int swz = lc & 7;

    f32x4 acc[MI][4] = {};

    for (int kb = 0; kb < K; kb += 64) {
        __syncthreads();
#pragma unroll
        for (int p0 = 0; p0 < 1024; p0 += 256) {
            int p = p0 + tid, row = p >> 3, cl = (p & 7) ^ (row & 7);
            gl_lds16(A + (size_t)(m0 + row) * K + kb + cl * 8, &lA[(size_t)(p0 + wave * 64) * 8]);
        }
#pragma unroll
        for (int p0 = 0; p0 < BN * 8; p0 += 256) {
            int p = p0 + tid, row = p >> 3, cl = (p & 7) ^ (row & 7);
            gl_lds16(B + (size_t)(n0 + row) * K + kb + cl * 8, &lB[(size_t)(p0 + wave * 64) * 8]);
        }
        __syncthreads();
#pragma unroll
        for (int k2 = 0; k2 < 2; ++k2) {
            bf16x8 af[MI], bfr[4];
#pragma unroll
            for (int t = 0; t < MI; ++t)
                af[t] = *(const bf16x8*)&lA[(wrow + t * 16 + lc) * 64 + ((quad + k2 * 4) ^ swz) * 8];
#pragma unroll
            for (int t = 0; t < 4; ++t)
                bfr[t] = *(const bf16x8*)&lB[(wcol + t * 16 + lc) * 64 + ((quad + k2 * 4) ^ swz) * 8];
#pragma unroll
            for (int mi = 0; mi < MI; ++mi)
#pragma unroll
                for (int ni = 0; ni < 4; ++ni)
                    acc[mi][ni] = __builtin_amdgcn_mfma_f32_16x16x32_bf16(af[mi], bfr[ni],
                                                                         acc[mi][ni], 0, 0, 0);
        }
    }

#pragma unroll
    for (int mi = 0; mi < MI; ++mi) {
#pragma unroll
        for (int r = 0; r < 4; ++r) {
            int m = m0 + wrow + mi * 16 + quad * 4 + r;
#pragma unroll
            for (int ni = 0; ni < 4; ++ni) {
                int n = n0 + wcol + ni * 16 + lc;
                float v = acc[mi][ni][r];
                if constexpr (EPI == 0) {
                    int b = m >> 11, s = m & 2047;
                    int which = n / DD, rem = n - which * DD;
                    int h = rem >> 6, d = rem & 63;
                    u16* dst = which == 0 ? Qb : (which == 1 ? Kb : Vb);
                    dst[((((size_t)b * HH + h) * SS + s) << 6) + d] = f2bf(v);
                } else if constexpr (EPI == 1) {
                    float g = 0.5f * v * (1.0f + erff(v * 0.70710678118654752f));
                    ((u16*)out)[(size_t)m * N + n] = f2bf(g);
                } else if constexpr (EPI == 2) {
                    ((float*)out)[(size_t)m * N + n] =
                        v + ((const float*)aux)[(size_t)m * N + n];
                } else {
                    ((float*)out)[(size_t)m * N + n] =
                        v + (float)(((const __bf16*)aux)[(size_t)m * N + n]);
                }
            }
        }
    }
}

// ---------------- V transpose: [B,H,S,D] -> [B,H,D,S] (bf16) ----------------
__global__ __launch_bounds__(256) void transpose_v(const u16* __restrict__ V,
                                                   u16* __restrict__ Vt) {
    __shared__ u16 t[32][33];
    int bh = blockIdx.z;
    int s0 = blockIdx.x * 32, d0 = blockIdx.y * 32;
    const u16* vb = V + (size_t)bh * SS * HD;
    u16* vtb = Vt + (size_t)bh * HD * SS;
    int tx = threadIdx.x & 31, ty = threadIdx.x >> 5;
#pragma unroll
    for (int i = 0; i < 32; i += 8) t[ty + i][tx] = vb[(size_t)(s0 + ty + i) * HD + d0 + tx];
    __syncthreads();
#pragma unroll
    for (int i = 0; i < 32; i += 8) vtb[(size_t)(d0 + ty + i) * SS + s0 + tx] = t[tx][ty + i];
}

// ---------------- flash attention (S^T, barrier-free K-loop) ----------------
// grid (S/128, B*H), 4 waves, 32 q-rows/wave, waves fully independent.
// K/V MFMA fragments are loaded DIRECTLY from global (coalesced 16 B/lane;
// cross-wave redundancy absorbed by L1: K+V tile = 16 KB < 32 KB L1).
// LDS only carries the P C-layout->A-layout round-trip (wave-private, no
// barrier). Round-3/4 LDS-staged versions were LDS-throughput-bound
// (~1150 LDS cyc/block-tile vs ~90 MFMA cyc); this splits traffic across
// the VMEM and LDS pipes and removes all __syncthreads from the loop.
__global__ __launch_bounds__(256) void attn_kernel(const u16* __restrict__ Q,
                                                   const u16* __restrict__ K,
                                                   const u16* __restrict__ Vt,
                                                   const float* __restrict__ maskbias,
                                                   u16* __restrict__ Ctx) {
    __shared__ __align__(16) u16 lP[4][32 * 72];
    const int tid = threadIdx.x, lane = tid & 63, wave = tid >> 6;
    const int quad = lane >> 4, lc = lane & 15;
    const int bh = blockIdx.y;
    const int b = bh / HH, h = bh - b * HH;
    const int q0 = blockIdx.x * 128 + wave * 32;
    const u16* Qg = Q + ((size_t)bh * SS + q0) * HD;
    const u16* Kg = K + (size_t)bh * SS * HD;
    const u16* Vg = Vt + (size_t)bh * HD * SS;
    const float* mbg = maskbias + b * SS;

    // Q fragments (B-operand): n = q = mi*16+lc, k = k2*32+quad*8+j
    bf16x8 qf[2][2];
#pragma unroll
    for (int mi = 0; mi < 2; ++mi)
#pragma unroll
        for (int k2 = 0; k2 < 2; ++k2)
            qf[mi][k2] = *(const bf16x8*)(Qg + (size_t)(mi * 16 + lc) * HD + k2 * 32 + quad * 8);

    bf16x8 onesf;
#pragma unroll
    for (int i = 0; i < 8; ++i) onesf[i] = (__bf16)1.0f;

    f32x4 oacc[2][4] = {};
    f32x4 lsum[2] = {};

    for (int j0 = 0; j0 < SS; j0 += 64) {
        // K fragments direct from global (A-operand: m = key = ni*16+lc)
        bf16x8 kf[4][2];
#pragma unroll
        for (int ni = 0; ni < 4; ++ni)
#pragma unroll
            for (int k2 = 0; k2 < 2; ++k2)
                kf[ni][k2] = *(const bf16x8*)(Kg + (size_t)(j0 + ni * 16 + lc) * HD + k2 * 32 + quad * 8);

        // S^T = K Q^T: per-lane q = mi*16+lc, key = ni*16+quad*4+r
        f32x4 sacc[4][2] = {};
#pragma unroll
        for (int k2 = 0; k2 < 2; ++k2)
#pragma unroll
            for (int ni = 0; ni < 4; ++ni) {
                sacc[ni][0] = __builtin_amdgcn_mfma_f32_16x16x32_bf16(kf[ni][k2], qf[0][k2], sacc[ni][0], 0, 0, 0);
                sacc[ni][1] = __builtin_amdgcn_mfma_f32_16x16x32_bf16(kf[ni][k2], qf[1][k2], sacc[ni][1], 0, 0, 0);
            }

        // V fragments direct from global (B-operand: n = d = ni*16+lc)
        bf16x8 vf[4][2];
#pragma unroll
        for (int ni = 0; ni < 4; ++ni)
#pragma unroll
            for (int k2 = 0; k2 < 2; ++k2)
                vf[ni][k2] = *(const bf16x8*)(Vg + (size_t)(ni * 16 + lc) * SS + j0 + k2 * 32 + quad * 8);

        // p = exp2(s*log2e/8 + mb[key]); pack via v_perm truncation -> lP
#pragma unroll
        for (int ni = 0; ni < 4; ++ni) {
            f32x4 mbv = *(const f32x4*)(mbg + j0 + ni * 16 + quad * 4);
#pragma unroll
            for (int mi = 0; mi < 2; ++mi) {
#pragma unroll
                for (int r = 0; r < 4; ++r)
                    sacc[ni][mi][r] = exp2f(fmaf(sacc[ni][mi][r], 0.180336880f, mbv[r]));
                u32 w0 = __builtin_amdgcn_perm(fas(sacc[ni][mi][1]), fas(sacc[ni][mi][0]), 0x07060302);
                u32 w1 = __builtin_amdgcn_perm(fas(sacc[ni][mi][3]), fas(sacc[ni][mi][2]), 0x07060302);
                *(uint2*)&lP[wave][(mi * 16 + lc) * 72 + ni * 16 + quad * 4] = make_uint2(w0, w1);
            }
        }

        // O += P V ; l += P * ones  (lP wave-private: no barrier)
#pragma unroll
        for (int k2 = 0; k2 < 2; ++k2) {
            bf16x8 pf0 = *(const bf16x8*)&lP[wave][(size_t)lc * 72 + k2 * 32 + quad * 8];
            bf16x8 pf1 = *(const bf16x8*)&lP[wave][(size_t)(16 + lc) * 72 + k2 * 32 + quad * 8];
            lsum[0] = __builtin_amdgcn_mfma_f32_16x16x32_bf16(pf0, onesf, lsum[0], 0, 0, 0);
            lsum[1] = __builtin_amdgcn_mfma_f32_16x16x32_bf16(pf1, onesf, lsum[1], 0, 0, 0);
#pragma unroll
            for (int ni = 0; ni < 4; ++ni) {
                oacc[0][ni] = __builtin_amdgcn_mfma_f32_16x16x32_bf16(pf0, vf[ni][k2], oacc[0][ni], 0, 0, 0);
                oacc[1][ni] = __builtin_amdgcn_mfma_f32_16x16x32_bf16(pf1, vf[ni][k2], oacc[1][ni], 0, 0, 0);
            }
        }
    }

    // epilogue: normalize and store (lsum in C-layout alongside oacc)
#pragma unroll
    for (int mi = 0; mi < 2; ++mi)
#pragma unroll
        for (int r = 0; r < 4; ++r) {
            float inv = 1.0f / lsum[mi][r];
            int s = q0 + mi * 16 + quad * 4 + r;
            size_t base = ((size_t)(b * SS + s)) * DD + h * HD;
#pragma unroll
            for (int ni = 0; ni < 4; ++ni)
                Ctx[base + ni * 16 + lc] = f2bf(oacc[mi][ni][r] * inv);
        }
}

// ---------------- LayerNorm over 768, one block per row ----------------
__global__ __launch_bounds__(256) void ln_kernel(const float* __restrict__ in,
                                                 const float* __restrict__ g,
                                                 const float* __restrict__ bb,
                                                 u16* __restrict__ out_bf,
                                                 float* __restrict__ out_f) {
    const int row = blockIdx.x, tid = threadIdx.x;
    const float* x = in + (size_t)row * DD;
    float v0 = x[tid], v1 = x[tid + 256], v2 = x[tid + 512];
    float s = v0 + v1 + v2;
    float q = v0 * v0 + v1 * v1 + v2 * v2;
#pragma unroll
    for (int o = 1; o < 64; o <<= 1) {
        s += __shfl_xor(s, o);
        q += __shfl_xor(q, o);
    }
    __shared__ float rs[4], rq[4];
    int wave = tid >> 6;
    if ((tid & 63) == 0) { rs[wave] = s; rq[wave] = q; }
    __syncthreads();
    s = rs[0] + rs[1] + rs[2] + rs[3];
    q = rq[0] + rq[1] + rq[2] + rq[3];
    float mu = s * (1.0f / DD);
    float var = q * (1.0f / DD) - mu * mu;
    float rstd = rsqrtf(var + 1e-5f);
#pragma unroll
    for (int j = 0; j < 3; ++j) {
        int col = tid + j * 256;
        float v = (j == 0 ? v0 : (j == 1 ? v1 : v2));
        float y = (v - mu) * rstd * g[col] + bb[col];
        if (out_bf) out_bf[(size_t)row * DD + col] = f2bf(y);
        if (out_f) out_f[(size_t)row * DD + col] = y;
    }
}

extern "C" void kernel_launch(void* const* d_in, const int* in_sizes, int n_in,
                              void* d_out, int out_size, void* d_ws, size_t ws_size,
                              hipStream_t stream) {
    const float* X    = (const float*)d_in[0];
    const int*   mask = (const int*)d_in[1];
    const float* Wq   = (const float*)d_in[2];
    const float* Wk   = (const float*)d_in[3];
    const float* Wv   = (const float*)d_in[4];
    const float* Wo   = (const float*)d_in[5];
    const float* W1   = (const float*)d_in[6];
    const float* W2   = (const float*)d_in[7];
    const float* ln_g = (const float*)d_in[8];
    const float* ln_b = (const float*)d_in[9];
    float* out = (float*)d_out;

    char* ws = (char*)d_ws;
    size_t off = 0;
    auto alloc = [&](size_t bytes) {
        void* p = ws + off;
        off += (bytes + 255) & ~(size_t)255;
        return p;
    };
    u16*   Xbf   = (u16*)alloc((size_t)ROWS * DD * 2);       // reused as Ctx
    u16*   Wqkvb = (u16*)alloc((size_t)3 * DD * DD * 2);
    u16*   Wob   = (u16*)alloc((size_t)DD * DD * 2);
    u16*   W1b   = (u16*)alloc((size_t)4 * DD * DD * 2);
    u16*   W2b   = (u16*)alloc((size_t)4 * DD * DD * 2);
    float* mbias = (float*)alloc((size_t)NB * SS * 4);
    u16*   Qb    = (u16*)alloc((size_t)ROWS * DD * 2);       // Qb..Vtb reused as Gb
    u16*   Kb    = (u16*)alloc((size_t)ROWS * DD * 2);
    u16*   Vb    = (u16*)alloc((size_t)ROWS * DD * 2);
    u16*   Vtb   = (u16*)alloc((size_t)ROWS * DD * 2);
    float* resid = (float*)alloc((size_t)ROWS * DD * 4);     // reused as h2
    u16*   n1b   = (u16*)alloc((size_t)ROWS * DD * 2);
    u16*   Gb    = Qb;          // 8192*3072*2 = 4 * (8192*768*2), fits Qb..Vtb
    u16*   Ctxb  = Xbf;
    float* h2    = resid;

    // fused casts + mask bias (13064 blocks)
    prep_kernel<<<dim3(13064), dim3(256), 0, stream>>>(
        X, Wq, Wk, Wv, Wo, W1, W2, mask,
        Xbf, Wqkvb, Wob, W1b, W2b, mbias);

    // QKV projection: [8192, 2304]
    gemm_bt<0, 128><<<dim3(3 * DD / 128, ROWS / 128), dim3(256), 0, stream>>>(
        Xbf, Wqkvb, ROWS, 3 * DD, DD, nullptr, nullptr, Qb, Kb, Vb);

    transpose_v<<<dim3(SS / 32, HD / 32, NB * HH), dim3(256), 0, stream>>>(Vb, Vtb);

    attn_kernel<<<dim3(SS / 128, NB * HH), dim3(256), 0, stream>>>(Qb, Kb, Vtb, mbias, Ctxb);

    // O projection + residual: resid = x + ctx @ Wo^T
    gemm_bt<2, 64><<<dim3(DD / 64, ROWS / 128), dim3(256), 0, stream>>>(
        Ctxb, Wob, ROWS, DD, DD, resid, X, nullptr, nullptr, nullptr);

    ln_kernel<<<dim3(ROWS), dim3(256), 0, stream>>>(resid, ln_g, ln_b, n1b, nullptr);

    // FFN1 + GELU: [8192, 3072] bf16
    gemm_bt<1, 128><<<dim3(4 * DD / 128, ROWS / 128), dim3(256), 0, stream>>>(
        n1b, W1b, ROWS, 4 * DD, DD, Gb, nullptr, nullptr, nullptr, nullptr);

    // FFN2 + residual: h2 = n1 + g @ W2^T
    gemm_bt<3, 64><<<dim3(DD / 64, ROWS / 128), dim3(256), 0, stream>>>(
        Gb, W2b, ROWS, DD, 4 * DD, h2, n1b, nullptr, nullptr, nullptr);

    ln_kernel<<<dim3(ROWS), dim3(256), 0, stream>>>(h2, ln_g, ln_b, nullptr, out);
}

// Round 6
// 454.015 us; speedup vs baseline: 1.2024x; 1.2024x over previous
//
#include <hip/hip_runtime.h>
#include <math.h>

typedef unsigned short u16;
typedef unsigned int u32;
typedef __bf16 bf16x8 __attribute__((ext_vector_type(8)));
typedef float f32x4 __attribute__((ext_vector_type(4)));

#define NB 4
#define SS 2048
#define DD 768
#define HH 12
#define HD 64
#define ROWS (NB*SS)   // 8192

__device__ __forceinline__ u16 f2bf(float f) {
    union { float f; unsigned u; } v; v.f = f;
    unsigned r = v.u + 0x7fffu + ((v.u >> 16) & 1u);
    return (u16)(r >> 16);
}
__device__ __forceinline__ u32 fas(float f) { union { float f; u32 u; } v; v.f = f; return v.u; }

__device__ __forceinline__ void gl_lds16(const void* g, void* l) {
    __builtin_amdgcn_global_load_lds((__attribute__((address_space(1))) void*)(g),
                                     (__attribute__((address_space(3))) void*)(l),
                                     16, 0, 0);
}

// ---------------- fused prep: all f32->bf16 casts + mask bias ----------------
__global__ __launch_bounds__(256) void prep_kernel(
        const float* __restrict__ X, const float* __restrict__ Wq,
        const float* __restrict__ Wk, const float* __restrict__ Wv,
        const float* __restrict__ Wo, const float* __restrict__ W1,
        const float* __restrict__ W2, const int* __restrict__ mask,
        u16* __restrict__ Xb, u16* __restrict__ Wqkvb, u16* __restrict__ Wob,
        u16* __restrict__ W1b, u16* __restrict__ W2b, float* __restrict__ mb) {
    const int blk = blockIdx.x, tid = threadIdx.x;
    const float* src; u16* dst; int idx;
    if (blk < 6144)       { src = X;  dst = Xb;               idx = blk * 1024 + tid * 4; }
    else if (blk < 6720)  { src = Wq; dst = Wqkvb;            idx = (blk - 6144) * 1024 + tid * 4; }
    else if (blk < 7296)  { src = Wk; dst = Wqkvb + DD * DD;  idx = (blk - 6720) * 1024 + tid * 4; }
    else if (blk < 7872)  { src = Wv; dst = Wqkvb + 2*DD*DD;  idx = (blk - 7296) * 1024 + tid * 4; }
    else if (blk < 8448)  { src = Wo; dst = Wob;              idx = (blk - 7872) * 1024 + tid * 4; }
    else if (blk < 10752) { src = W1; dst = W1b;              idx = (blk - 8448) * 1024 + tid * 4; }
    else if (blk < 13056) { src = W2; dst = W2b;              idx = (blk - 10752) * 1024 + tid * 4; }
    else {
        int i = (blk - 13056) * 1024 + tid * 4;
        float4 o;
        o.x = mask[i]     == 0 ? -1e30f : 0.0f;
        o.y = mask[i + 1] == 0 ? -1e30f : 0.0f;
        o.z = mask[i + 2] == 0 ? -1e30f : 0.0f;
        o.w = mask[i + 3] == 0 ? -1e30f : 0.0f;
        *(float4*)&mb[i] = o;
        return;
    }
    float4 v = *(const float4*)&src[idx];
    ushort4 o;
    o.x = f2bf(v.x); o.y = f2bf(v.y); o.z = f2bf(v.z); o.w = f2bf(v.w);
    *(ushort4*)&dst[idx] = o;
}

// ---------------- GEMM: C[M,N] = A[M,K] (bf16) * B[N,K]^T (bf16) ----------------
// 128xBN tile, BK=64, 4 waves. Chunk-swizzled LDS (phys = c ^ (row&7)).
// EPI 0: scatter to Q/K [B,H,S,D] and V TRANSPOSED [B,H,D,S] (kills transpose_v)
template <int EPI, int BN>
__global__ __launch_bounds__(256) void gemm_bt(const u16* __restrict__ A,
                                               const u16* __restrict__ B,
                                               int M, int N, int K,
                                               void* __restrict__ out,
                                               const void* __restrict__ aux,
                                               u16* __restrict__ Qb,
                                               u16* __restrict__ Kb,
                                               u16* __restrict__ Vtb) {
    __shared__ __align__(16) u16 lA[128 * 64];
    __shared__ __align__(16) u16 lB[BN * 64];
    constexpr int MI = (BN == 128) ? 4 : 2;
    const int tid = threadIdx.x;
    const int lane = tid & 63, wave = tid >> 6;
    const int quad = lane >> 4, lc = lane & 15;
    const int m0 = blockIdx.y * 128, n0 = blockIdx.x * BN;
    const int wrow = (BN == 128) ? (wave >> 1) * 64 : wave * 32;
    const int wcol = (BN == 128) ? (wave & 1) * 64 : 0;
    const int swz = lc & 7;

    f32x4 acc[MI][4] = {};

    for (int kb = 0; kb < K; kb += 64) {
        __syncthreads();
#pragma unroll
        for (int p0 = 0; p0 < 1024; p0 += 256) {
            int p = p0 + tid, row = p >> 3, cl = (p & 7) ^ (row & 7);
            gl_lds16(A + (size_t)(m0 + row) * K + kb + cl * 8, &lA[(size_t)(p0 + wave * 64) * 8]);
        }
#pragma unroll
        for (int p0 = 0; p0 < BN * 8; p0 += 256) {
            int p = p0 + tid, row = p >> 3, cl = (p & 7) ^ (row & 7);
            gl_lds16(B + (size_t)(n0 + row) * K + kb + cl * 8, &lB[(size_t)(p0 + wave * 64) * 8]);
        }
        __syncthreads();
#pragma unroll
        for (int k2 = 0; k2 < 2; ++k2) {
            bf16x8 af[MI], bfr[4];
#pragma unroll
            for (int t = 0; t < MI; ++t)
                af[t] = *(const bf16x8*)&lA[(wrow + t * 16 + lc) * 64 + ((quad + k2 * 4) ^ swz) * 8];
#pragma unroll
            for (int t = 0; t < 4; ++t)
                bfr[t] = *(const bf16x8*)&lB[(wcol + t * 16 + lc) * 64 + ((quad + k2 * 4) ^ swz) * 8];
#pragma unroll
            for (int mi = 0; mi < MI; ++mi)
#pragma unroll
                for (int ni = 0; ni < 4; ++ni)
                    acc[mi][ni] = __builtin_amdgcn_mfma_f32_16x16x32_bf16(af[mi], bfr[ni],
                                                                         acc[mi][ni], 0, 0, 0);
        }
    }

#pragma unroll
    for (int mi = 0; mi < MI; ++mi) {
#pragma unroll
        for (int r = 0; r < 4; ++r) {
            int m = m0 + wrow + mi * 16 + quad * 4 + r;
#pragma unroll
            for (int ni = 0; ni < 4; ++ni) {
                int n = n0 + wcol + ni * 16 + lc;
                float v = acc[mi][ni][r];
                if constexpr (EPI == 0) {
                    int b = m >> 11, s = m & 2047;
                    int which = n / DD, rem = n - which * DD;
                    int h = rem >> 6, d = rem & 63;
                    if (which == 2)
                        Vtb[((((size_t)b * HH + h) * HD + d) << 11) + s] = f2bf(v);
                    else {
                        u16* dst = which == 0 ? Qb : Kb;
                        dst[((((size_t)b * HH + h) * SS + s) << 6) + d] = f2bf(v);
                    }
                } else if constexpr (EPI == 1) {
                    float g = 0.5f * v * (1.0f + erff(v * 0.70710678118654752f));
                    ((u16*)out)[(size_t)m * N + n] = f2bf(g);
                } else if constexpr (EPI == 2) {
                    ((float*)out)[(size_t)m * N + n] =
                        v + ((const float*)aux)[(size_t)m * N + n];
                } else {
                    ((float*)out)[(size_t)m * N + n] =
                        v + (float)(((const __bf16*)aux)[(size_t)m * N + n]);
                }
            }
        }
    }
}

// ---------------- flash attention (S^T, double-buffered K/V staging) ----------------
// grid (S/128, B*H) = 768 blocks, 4 waves, 32 q-rows/wave.
// Iteration body: [barrier] [issue stage(t+1) -> buf^1] [compute(t) from buf].
// The compiler's vmcnt(0) drain before the next barrier lands AFTER a full
// tile of compute, so staging latency is hidden (round-3's stall). LDS =
// 2x16KB K/V + 18.4KB P = ~51 KB -> same 3 blocks/CU as round 3.
__global__ __launch_bounds__(256) void attn_kernel(const u16* __restrict__ Q,
                                                   const u16* __restrict__ K,
                                                   const u16* __restrict__ Vt,
                                                   const float* __restrict__ maskbias,
                                                   u16* __restrict__ Ctx) {
    __shared__ __align__(16) u16 lK[2][64 * 64];
    __shared__ __align__(16) u16 lV[2][64 * 64];   // [d][key]
    __shared__ __align__(16) u16 lP[4][32 * 72];
    const int tid = threadIdx.x, lane = tid & 63, wave = tid >> 6;
    const int quad = lane >> 4, lc = lane & 15;
    const int bh = blockIdx.y;
    const int b = bh / HH, h = bh - b * HH;
    const int q0 = blockIdx.x * 128;
    const u16* Qg = Q + ((size_t)bh * SS + q0 + wave * 32) * HD;
    const u16* Kg = K + (size_t)bh * SS * HD;
    const u16* Vg = Vt + (size_t)bh * HD * SS;
    const float* mbg = maskbias + b * SS;
    const int sw = lc & 7;

    const int srow = tid >> 3, scl = (tid & 7) ^ (srow & 7);
    const int srow2 = (256 + tid) >> 3, scl2 = (tid & 7) ^ (srow2 & 7);

    // Q fragments (B-operand): n = q = mi*16+lc, k = k2*32+quad*8+j
    bf16x8 qf[2][2];
#pragma unroll
    for (int mi = 0; mi < 2; ++mi)
#pragma unroll
        for (int k2 = 0; k2 < 2; ++k2)
            qf[mi][k2] = *(const bf16x8*)(Qg + (size_t)(mi * 16 + lc) * HD + k2 * 32 + quad * 8);

    bf16x8 onesf;
#pragma unroll
    for (int i = 0; i < 8; ++i) onesf[i] = (__bf16)1.0f;

    f32x4 oacc[2][4] = {};
    f32x4 lsum[2] = {};

    // stage tile 0 into buffer 0
    {
        gl_lds16(Kg + (size_t)srow * HD + scl * 8,        &lK[0][(size_t)(wave * 64) * 8]);
        gl_lds16(Vg + (size_t)srow * SS + scl * 8,        &lV[0][(size_t)(wave * 64) * 8]);
        gl_lds16(Kg + (size_t)srow2 * HD + scl2 * 8,      &lK[0][(size_t)(256 + wave * 64) * 8]);
        gl_lds16(Vg + (size_t)srow2 * SS + scl2 * 8,      &lV[0][(size_t)(256 + wave * 64) * 8]);
    }

    for (int j0 = 0; j0 < SS; j0 += 64) {
        const int cur = (j0 >> 6) & 1;
        __syncthreads();   // vmcnt(0) drain: stage(j0) complete; overlapped with prior tile's compute
        if (j0 + 64 < SS) {
            const int nxt = cur ^ 1;
            gl_lds16(Kg + (size_t)(j0 + 64 + srow) * HD + scl * 8,   &lK[nxt][(size_t)(wave * 64) * 8]);
            gl_lds16(Vg + (size_t)srow * SS + j0 + 64 + scl * 8,     &lV[nxt][(size_t)(wave * 64) * 8]);
            gl_lds16(Kg + (size_t)(j0 + 64 + srow2) * HD + scl2 * 8, &lK[nxt][(size_t)(256 + wave * 64) * 8]);
            gl_lds16(Vg + (size_t)srow2 * SS + j0 + 64 + scl2 * 8,   &lV[nxt][(size_t)(256 + wave * 64) * 8]);
        }

        // S^T = K Q^T: per-lane q = mi*16+lc, key = ni*16+quad*4+r
        f32x4 sacc[4][2] = {};
#pragma unroll
        for (int k2 = 0; k2 < 2; ++k2)
#pragma unroll
            for (int ni = 0; ni < 4; ++ni) {
                bf16x8 kf = *(const bf16x8*)&lK[cur][(ni * 16 + lc) * 64 + ((quad + k2 * 4) ^ sw) * 8];
                sacc[ni][0] = __builtin_amdgcn_mfma_f32_16x16x32_bf16(kf, qf[0][k2], sacc[ni][0], 0, 0, 0);
                sacc[ni][1] = __builtin_amdgcn_mfma_f32_16x16x32_bf16(kf, qf[1][k2], sacc[ni][1], 0, 0, 0);
            }

        // p = exp2(s*log2e/8 + mb[key]); pack via v_perm truncation -> lP
#pragma unroll
        for (int ni = 0; ni < 4; ++ni) {
            f32x4 mbv = *(const f32x4*)(mbg + j0 + ni * 16 + quad * 4);
#pragma unroll
            for (int mi = 0; mi < 2; ++mi) {
#pragma unroll
                for (int r = 0; r < 4; ++r)
                    sacc[ni][mi][r] = exp2f(fmaf(sacc[ni][mi][r], 0.180336880f, mbv[r]));
                u32 w0 = __builtin_amdgcn_perm(fas(sacc[ni][mi][1]), fas(sacc[ni][mi][0]), 0x07060302);
                u32 w1 = __builtin_amdgcn_perm(fas(sacc[ni][mi][3]), fas(sacc[ni][mi][2]), 0x07060302);
                *(uint2*)&lP[wave][(mi * 16 + lc) * 72 + ni * 16 + quad * 4] = make_uint2(w0, w1);
            }
        }

        // O += P V ; l += P * ones  (lP wave-private: no barrier)
#pragma unroll
        for (int k2 = 0; k2 < 2; ++k2) {
            bf16x8 pf0 = *(const bf16x8*)&lP[wave][(size_t)lc * 72 + k2 * 32 + quad * 8];
            bf16x8 pf1 = *(const bf16x8*)&lP[wave][(size_t)(16 + lc) * 72 + k2 * 32 + quad * 8];
            lsum[0] = __builtin_amdgcn_mfma_f32_16x16x32_bf16(pf0, onesf, lsum[0], 0, 0, 0);
            lsum[1] = __builtin_amdgcn_mfma_f32_16x16x32_bf16(pf1, onesf, lsum[1], 0, 0, 0);
#pragma unroll
            for (int ni = 0; ni < 4; ++ni) {
                bf16x8 vf = *(const bf16x8*)&lV[cur][(ni * 16 + lc) * 64 + ((quad + k2 * 4) ^ sw) * 8];
                oacc[0][ni] = __builtin_amdgcn_mfma_f32_16x16x32_bf16(pf0, vf, oacc[0][ni], 0, 0, 0);
                oacc[1][ni] = __builtin_amdgcn_mfma_f32_16x16x32_bf16(pf1, vf, oacc[1][ni], 0, 0, 0);
            }
        }
    }

    // epilogue: normalize and store (lsum in C-layout alongside oacc)
#pragma unroll
    for (int mi = 0; mi < 2; ++mi)
#pragma unroll
        for (int r = 0; r < 4; ++r) {
            float inv = 1.0f / lsum[mi][r];
            int s = q0 + wave * 32 + mi * 16 + quad * 4 + r;
            size_t base = ((size_t)(b * SS + s)) * DD + h * HD;
#pragma unroll
            for (int ni = 0; ni < 4; ++ni)
                Ctx[base + ni * 16 + lc] = f2bf(oacc[mi][ni][r] * inv);
        }
}

// ---------------- LayerNorm over 768, one block per row ----------------
__global__ __launch_bounds__(256) void ln_kernel(const float* __restrict__ in,
                                                 const float* __restrict__ g,
                                                 const float* __restrict__ bb,
                                                 u16* __restrict__ out_bf,
                                                 float* __restrict__ out_f) {
    const int row = blockIdx.x, tid = threadIdx.x;
    const float* x = in + (size_t)row * DD;
    float v0 = x[tid], v1 = x[tid + 256], v2 = x[tid + 512];
    float s = v0 + v1 + v2;
    float q = v0 * v0 + v1 * v1 + v2 * v2;
#pragma unroll
    for (int o = 1; o < 64; o <<= 1) {
        s += __shfl_xor(s, o);
        q += __shfl_xor(q, o);
    }
    __shared__ float rs[4], rq[4];
    int wave = tid >> 6;
    if ((tid & 63) == 0) { rs[wave] = s; rq[wave] = q; }
    __syncthreads();
    s = rs[0] + rs[1] + rs[2] + rs[3];
    q = rq[0] + rq[1] + rq[2] + rq[3];
    float mu = s * (1.0f / DD);
    float var = q * (1.0f / DD) - mu * mu;
    float rstd = rsqrtf(var + 1e-5f);
#pragma unroll
    for (int j = 0; j < 3; ++j) {
        int col = tid + j * 256;
        float v = (j == 0 ? v0 : (j == 1 ? v1 : v2));
        float y = (v - mu) * rstd * g[col] + bb[col];
        if (out_bf) out_bf[(size_t)row * DD + col] = f2bf(y);
        if (out_f) out_f[(size_t)row * DD + col] = y;
    }
}

extern "C" void kernel_launch(void* const* d_in, const int* in_sizes, int n_in,
                              void* d_out, int out_size, void* d_ws, size_t ws_size,
                              hipStream_t stream) {
    const float* X    = (const float*)d_in[0];
    const int*   mask = (const int*)d_in[1];
    const float* Wq   = (const float*)d_in[2];
    const float* Wk   = (const float*)d_in[3];
    const float* Wv   = (const float*)d_in[4];
    const float* Wo   = (const float*)d_in[5];
    const float* W1   = (const float*)d_in[6];
    const float* W2   = (const float*)d_in[7];
    const float* ln_g = (const float*)d_in[8];
    const float* ln_b = (const float*)d_in[9];
    float* out = (float*)d_out;

    char* ws = (char*)d_ws;
    size_t off = 0;
    auto alloc = [&](size_t bytes) {
        void* p = ws + off;
        off += (bytes + 255) & ~(size_t)255;
        return p;
    };
    u16*   Xbf   = (u16*)alloc((size_t)ROWS * DD * 2);       // reused as Ctx
    u16*   Wqkvb = (u16*)alloc((size_t)3 * DD * DD * 2);
    u16*   Wob   = (u16*)alloc((size_t)DD * DD * 2);
    u16*   W1b   = (u16*)alloc((size_t)4 * DD * DD * 2);
    u16*   W2b   = (u16*)alloc((size_t)4 * DD * DD * 2);
    float* mbias = (float*)alloc((size_t)NB * SS * 4);
    u16*   Qb    = (u16*)alloc((size_t)ROWS * DD * 2);       // Qb..spare reused as Gb
    u16*   Kb    = (u16*)alloc((size_t)ROWS * DD * 2);
    u16*   Vtb   = (u16*)alloc((size_t)ROWS * DD * 2);
    u16*   spare = (u16*)alloc((size_t)ROWS * DD * 2);       // pads Gb to 48 MB
    float* resid = (float*)alloc((size_t)ROWS * DD * 4);     // reused as h2
    u16*   n1b   = (u16*)alloc((size_t)ROWS * DD * 2);
    u16*   Gb    = Qb;          // 8192*3072*2 = 4 * (8192*768*2) = Qb..spare
    u16*   Ctxb  = Xbf;
    float* h2    = resid;
    (void)spare;

    // fused casts + mask bias (13064 blocks)
    prep_kernel<<<dim3(13064), dim3(256), 0, stream>>>(
        X, Wq, Wk, Wv, Wo, W1, W2, mask,
        Xbf, Wqkvb, Wob, W1b, W2b, mbias);

    // QKV projection: [8192, 2304]; V written pre-transposed [B,H,D,S]
    gemm_bt<0, 128><<<dim3(3 * DD / 128, ROWS / 128), dim3(256), 0, stream>>>(
        Xbf, Wqkvb, ROWS, 3 * DD, DD, nullptr, nullptr, Qb, Kb, Vtb);

    attn_kernel<<<dim3(SS / 128, NB * HH), dim3(256), 0, stream>>>(Qb, Kb, Vtb, mbias, Ctxb);

    // O projection + residual: resid = x + ctx @ Wo^T
    gemm_bt<2, 64><<<dim3(DD / 64, ROWS / 128), dim3(256), 0, stream>>>(
        Ctxb, Wob, ROWS, DD, DD, resid, X, nullptr, nullptr, nullptr);

    ln_kernel<<<dim3(ROWS), dim3(256), 0, stream>>>(resid, ln_g, ln_b, n1b, nullptr);

    // FFN1 + GELU: [8192, 3072] bf16
    gemm_bt<1, 128><<<dim3(4 * DD / 128, ROWS / 128), dim3(256), 0, stream>>>(
        n1b, W1b, ROWS, 4 * DD, DD, Gb, nullptr, nullptr, nullptr, nullptr);

    // FFN2 + residual: h2 = n1 + g @ W2^T
    gemm_bt<3, 64><<<dim3(DD / 64, ROWS / 128), dim3(256), 0, stream>>>(
        Gb, W2b, ROWS, DD, 4 * DD, h2, n1b, nullptr, nullptr, nullptr);

    ln_kernel<<<dim3(ROWS), dim3(256), 0, stream>>>(h2, ln_g, ln_b, nullptr, out);
}

// Round 7
// 411.648 us; speedup vs baseline: 1.3262x; 1.1029x over previous
//
#include <hip/hip_runtime.h>
#include <math.h>

typedef unsigned short u16;
typedef unsigned int u32;
typedef __bf16 bf16x8 __attribute__((ext_vector_type(8)));
typedef float f32x4 __attribute__((ext_vector_type(4)));

#define NB 4
#define SS 2048
#define DD 768
#define HH 12
#define HD 64
#define ROWS (NB*SS)   // 8192

__device__ __forceinline__ u16 f2bf(float f) {
    union { float f; unsigned u; } v; v.f = f;
    unsigned r = v.u + 0x7fffu + ((v.u >> 16) & 1u);
    return (u16)(r >> 16);
}
__device__ __forceinline__ u32 fas(float f) { union { float f; u32 u; } v; v.f = f; return v.u; }

__device__ __forceinline__ void gl_lds16(const void* g, void* l) {
    __builtin_amdgcn_global_load_lds((__attribute__((address_space(1))) void*)(g),
                                     (__attribute__((address_space(3))) void*)(l),
                                     16, 0, 0);
}

// ---------------- fused prep: all f32->bf16 casts + mask bias ----------------
__global__ __launch_bounds__(256) void prep_kernel(
        const float* __restrict__ X, const float* __restrict__ Wq,
        const float* __restrict__ Wk, const float* __restrict__ Wv,
        const float* __restrict__ Wo, const float* __restrict__ W1,
        const float* __restrict__ W2, const int* __restrict__ mask,
        u16* __restrict__ Xb, u16* __restrict__ Wqkvb, u16* __restrict__ Wob,
        u16* __restrict__ W1b, u16* __restrict__ W2b, float* __restrict__ mb) {
    const int blk = blockIdx.x, tid = threadIdx.x;
    const float* src; u16* dst; int idx;
    if (blk < 6144)       { src = X;  dst = Xb;               idx = blk * 1024 + tid * 4; }
    else if (blk < 6720)  { src = Wq; dst = Wqkvb;            idx = (blk - 6144) * 1024 + tid * 4; }
    else if (blk < 7296)  { src = Wk; dst = Wqkvb + DD * DD;  idx = (blk - 6720) * 1024 + tid * 4; }
    else if (blk < 7872)  { src = Wv; dst = Wqkvb + 2*DD*DD;  idx = (blk - 7296) * 1024 + tid * 4; }
    else if (blk < 8448)  { src = Wo; dst = Wob;              idx = (blk - 7872) * 1024 + tid * 4; }
    else if (blk < 10752) { src = W1; dst = W1b;              idx = (blk - 8448) * 1024 + tid * 4; }
    else if (blk < 13056) { src = W2; dst = W2b;              idx = (blk - 10752) * 1024 + tid * 4; }
    else {
        int i = (blk - 13056) * 1024 + tid * 4;
        float4 o;
        o.x = mask[i]     == 0 ? -1e30f : 0.0f;
        o.y = mask[i + 1] == 0 ? -1e30f : 0.0f;
        o.z = mask[i + 2] == 0 ? -1e30f : 0.0f;
        o.w = mask[i + 3] == 0 ? -1e30f : 0.0f;
        *(float4*)&mb[i] = o;
        return;
    }
    float4 v = *(const float4*)&src[idx];
    ushort4 o;
    o.x = f2bf(v.x); o.y = f2bf(v.y); o.z = f2bf(v.z); o.w = f2bf(v.w);
    *(ushort4*)&dst[idx] = o;
}

// ---------------- GEMM: C[M,N] = A[M,K] (bf16) * B[N,K]^T (bf16) ----------------
// 128xBN tile, BK=64, 4 waves. Chunk-swizzled LDS (phys = c ^ (row&7)).
// EPI 0: scatter to Q/K/V [B,H,S,D] bf16 (coalesced along d)
template <int EPI, int BN>
__global__ __launch_bounds__(256) void gemm_bt(const u16* __restrict__ A,
                                               const u16* __restrict__ B,
                                               int M, int N, int K,
                                               void* __restrict__ out,
                                               const void* __restrict__ aux,
                                               u16* __restrict__ Qb,
                                               u16* __restrict__ Kb,
                                               u16* __restrict__ Vb) {
    __shared__ __align__(16) u16 lA[128 * 64];
    __shared__ __align__(16) u16 lB[BN * 64];
    constexpr int MI = (BN == 128) ? 4 : 2;
    const int tid = threadIdx.x;
    const int lane = tid & 63, wave = tid >> 6;
    const int quad = lane >> 4, lc = lane & 15;
    const int m0 = blockIdx.y * 128, n0 = blockIdx.x * BN;
    const int wrow = (BN == 128) ? (wave >> 1) * 64 : wave * 32;
    const int wcol = (BN == 128) ? (wave & 1) * 64 : 0;
    const int swz = lc & 7;

    f32x4 acc[MI][4] = {};

    for (int kb = 0; kb < K; kb += 64) {
        __syncthreads();
#pragma unroll
        for (int p0 = 0; p0 < 1024; p0 += 256) {
            int p = p0 + tid, row = p >> 3, cl = (p & 7) ^ (row & 7);
            gl_lds16(A + (size_t)(m0 + row) * K + kb + cl * 8, &lA[(size_t)(p0 + wave * 64) * 8]);
        }
#pragma unroll
        for (int p0 = 0; p0 < BN * 8; p0 += 256) {
            int p = p0 + tid, row = p >> 3, cl = (p & 7) ^ (row & 7);
            gl_lds16(B + (size_t)(n0 + row) * K + kb + cl * 8, &lB[(size_t)(p0 + wave * 64) * 8]);
        }
        __syncthreads();
#pragma unroll
        for (int k2 = 0; k2 < 2; ++k2) {
            bf16x8 af[MI], bfr[4];
#pragma unroll
            for (int t = 0; t < MI; ++t)
                af[t] = *(const bf16x8*)&lA[(wrow + t * 16 + lc) * 64 + ((quad + k2 * 4) ^ swz) * 8];
#pragma unroll
            for (int t = 0; t < 4; ++t)
                bfr[t] = *(const bf16x8*)&lB[(wcol + t * 16 + lc) * 64 + ((quad + k2 * 4) ^ swz) * 8];
#pragma unroll
            for (int mi = 0; mi < MI; ++mi)
#pragma unroll
                for (int ni = 0; ni < 4; ++ni)
                    acc[mi][ni] = __builtin_amdgcn_mfma_f32_16x16x32_bf16(af[mi], bfr[ni],
                                                                         acc[mi][ni], 0, 0, 0);
        }
    }

#pragma unroll
    for (int mi = 0; mi < MI; ++mi) {
#pragma unroll
        for (int r = 0; r < 4; ++r) {
            int m = m0 + wrow + mi * 16 + quad * 4 + r;
#pragma unroll
            for (int ni = 0; ni < 4; ++ni) {
                int n = n0 + wcol + ni * 16 + lc;
                float v = acc[mi][ni][r];
                if constexpr (EPI == 0) {
                    int b = m >> 11, s = m & 2047;
                    int which = n / DD, rem = n - which * DD;
                    int h = rem >> 6, d = rem & 63;
                    u16* dst = which == 0 ? Qb : (which == 1 ? Kb : Vb);
                    dst[((((size_t)b * HH + h) * SS + s) << 6) + d] = f2bf(v);
                } else if constexpr (EPI == 1) {
                    float g = 0.5f * v * (1.0f + erff(v * 0.70710678118654752f));
                    ((u16*)out)[(size_t)m * N + n] = f2bf(g);
                } else if constexpr (EPI == 2) {
                    ((float*)out)[(size_t)m * N + n] =
                        v + ((const float*)aux)[(size_t)m * N + n];
                } else {
                    ((float*)out)[(size_t)m * N + n] =
                        v + (float)(((const __bf16*)aux)[(size_t)m * N + n]);
                }
            }
        }
    }
}

// ---------------- V transpose: [B,H,S,D] -> [B,H,D,S] (bf16) ----------------
__global__ __launch_bounds__(256) void transpose_v(const u16* __restrict__ V,
                                                   u16* __restrict__ Vt) {
    __shared__ u16 t[32][33];
    int bh = blockIdx.z;
    int s0 = blockIdx.x * 32, d0 = blockIdx.y * 32;
    const u16* vb = V + (size_t)bh * SS * HD;
    u16* vtb = Vt + (size_t)bh * HD * SS;
    int tx = threadIdx.x & 31, ty = threadIdx.x >> 5;
#pragma unroll
    for (int i = 0; i < 32; i += 8) t[ty + i][tx] = vb[(size_t)(s0 + ty + i) * HD + d0 + tx];
    __syncthreads();
#pragma unroll
    for (int i = 0; i < 32; i += 8) vtb[(size_t)(d0 + ty + i) * SS + s0 + tx] = t[tx][ty + i];
}

// ---------------- flash attention (S^T, dbuf staging, raw v_exp_f32) ----------------
// grid (S/128, B*H) = 768 blocks (3/CU), 4 waves, 32 q-rows/wave.
__global__ __launch_bounds__(256) void attn_kernel(const u16* __restrict__ Q,
                                                   const u16* __restrict__ K,
                                                   const u16* __restrict__ Vt,
                                                   const float* __restrict__ maskbias,
                                                   u16* __restrict__ Ctx) {
    __shared__ __align__(16) u16 lK[2][64 * 64];
    __shared__ __align__(16) u16 lV[2][64 * 64];   // [d][key]
    __shared__ __align__(16) u16 lP[4][32 * 72];
    const int tid = threadIdx.x, lane = tid & 63, wave = tid >> 6;
    const int quad = lane >> 4, lc = lane & 15;
    const int bh = blockIdx.y;
    const int b = bh / HH, h = bh - b * HH;
    const int q0 = blockIdx.x * 128;
    const u16* Qg = Q + ((size_t)bh * SS + q0 + wave * 32) * HD;
    const u16* Kg = K + (size_t)bh * SS * HD;
    const u16* Vg = Vt + (size_t)bh * HD * SS;
    const float* mbg = maskbias + b * SS;
    const int sw = lc & 7;

    const int srow = tid >> 3, scl = (tid & 7) ^ (srow & 7);
    const int srow2 = (256 + tid) >> 3, scl2 = (tid & 7) ^ (srow2 & 7);

    // Q fragments (B-operand): n = q = mi*16+lc, k = k2*32+quad*8+j
    bf16x8 qf[2][2];
#pragma unroll
    for (int mi = 0; mi < 2; ++mi)
#pragma unroll
        for (int k2 = 0; k2 < 2; ++k2)
            qf[mi][k2] = *(const bf16x8*)(Qg + (size_t)(mi * 16 + lc) * HD + k2 * 32 + quad * 8);

    bf16x8 onesf;
#pragma unroll
    for (int i = 0; i < 8; ++i) onesf[i] = (__bf16)1.0f;

    f32x4 oacc[2][4] = {};
    f32x4 lsum[2] = {};

    // stage tile 0 into buffer 0
    {
        gl_lds16(Kg + (size_t)srow * HD + scl * 8,        &lK[0][(size_t)(wave * 64) * 8]);
        gl_lds16(Vg + (size_t)srow * SS + scl * 8,        &lV[0][(size_t)(wave * 64) * 8]);
        gl_lds16(Kg + (size_t)srow2 * HD + scl2 * 8,      &lK[0][(size_t)(256 + wave * 64) * 8]);
        gl_lds16(Vg + (size_t)srow2 * SS + scl2 * 8,      &lV[0][(size_t)(256 + wave * 64) * 8]);
    }

    for (int j0 = 0; j0 < SS; j0 += 64) {
        const int cur = (j0 >> 6) & 1;
        __syncthreads();   // stage(j0) complete; drain overlapped with prior tile's compute
        if (j0 + 64 < SS) {
            const int nxt = cur ^ 1;
            gl_lds16(Kg + (size_t)(j0 + 64 + srow) * HD + scl * 8,   &lK[nxt][(size_t)(wave * 64) * 8]);
            gl_lds16(Vg + (size_t)srow * SS + j0 + 64 + scl * 8,     &lV[nxt][(size_t)(wave * 64) * 8]);
            gl_lds16(Kg + (size_t)(j0 + 64 + srow2) * HD + scl2 * 8, &lK[nxt][(size_t)(256 + wave * 64) * 8]);
            gl_lds16(Vg + (size_t)srow2 * SS + j0 + 64 + scl2 * 8,   &lV[nxt][(size_t)(256 + wave * 64) * 8]);
        }

        // S^T = K Q^T: per-lane q = mi*16+lc, key = ni*16+quad*4+r
        f32x4 sacc[4][2] = {};
#pragma unroll
        for (int k2 = 0; k2 < 2; ++k2)
#pragma unroll
            for (int ni = 0; ni < 4; ++ni) {
                bf16x8 kf = *(const bf16x8*)&lK[cur][(ni * 16 + lc) * 64 + ((quad + k2 * 4) ^ sw) * 8];
                sacc[ni][0] = __builtin_amdgcn_mfma_f32_16x16x32_bf16(kf, qf[0][k2], sacc[ni][0], 0, 0, 0);
                sacc[ni][1] = __builtin_amdgcn_mfma_f32_16x16x32_bf16(kf, qf[1][k2], sacc[ni][1], 0, 0, 0);
            }

        // p = exp2(s*log2e/8 + mb[key]) via RAW v_exp_f32 (args bounded;
        // masked: fma -> -1e30, v_exp -> 0). libm exp2f's OCML wrapper was
        // the round-3..6 VALU tax.
#pragma unroll
        for (int ni = 0; ni < 4; ++ni) {
            f32x4 mbv = *(const f32x4*)(mbg + j0 + ni * 16 + quad * 4);
#pragma unroll
            for (int mi = 0; mi < 2; ++mi) {
#pragma unroll
                for (int r = 0; r < 4; ++r)
                    sacc[ni][mi][r] = __builtin_amdgcn_exp2f(fmaf(sacc[ni][mi][r], 0.180336880f, mbv[r]));
                u32 w0 = __builtin_amdgcn_perm(fas(sacc[ni][mi][1]), fas(sacc[ni][mi][0]), 0x07060302);
                u32 w1 = __builtin_amdgcn_perm(fas(sacc[ni][mi][3]), fas(sacc[ni][mi][2]), 0x07060302);
                *(uint2*)&lP[wave][(mi * 16 + lc) * 72 + ni * 16 + quad * 4] = make_uint2(w0, w1);
            }
        }

        // O += P V ; l += P * ones  (lP wave-private: no barrier)
#pragma unroll
        for (int k2 = 0; k2 < 2; ++k2) {
            bf16x8 pf0 = *(const bf16x8*)&lP[wave][(size_t)lc * 72 + k2 * 32 + quad * 8];
            bf16x8 pf1 = *(const bf16x8*)&lP[wave][(size_t)(16 + lc) * 72 + k2 * 32 + quad * 8];
            lsum[0] = __builtin_amdgcn_mfma_f32_16x16x32_bf16(pf0, onesf, lsum[0], 0, 0, 0);
            lsum[1] = __builtin_amdgcn_mfma_f32_16x16x32_bf16(pf1, onesf, lsum[1], 0, 0, 0);
#pragma unroll
            for (int ni = 0; ni < 4; ++ni) {
                bf16x8 vf = *(const bf16x8*)&lV[cur][(ni * 16 + lc) * 64 + ((quad + k2 * 4) ^ sw) * 8];
                oacc[0][ni] = __builtin_amdgcn_mfma_f32_16x16x32_bf16(pf0, vf, oacc[0][ni], 0, 0, 0);
                oacc[1][ni] = __builtin_amdgcn_mfma_f32_16x16x32_bf16(pf1, vf, oacc[1][ni], 0, 0, 0);
            }
        }
    }

    // epilogue: normalize and store (lsum in C-layout alongside oacc)
#pragma unroll
    for (int mi = 0; mi < 2; ++mi)
#pragma unroll
        for (int r = 0; r < 4; ++r) {
            float inv = 1.0f / lsum[mi][r];
            int s = q0 + wave * 32 + mi * 16 + quad * 4 + r;
            size_t base = ((size_t)(b * SS + s)) * DD + h * HD;
#pragma unroll
            for (int ni = 0; ni < 4; ++ni)
                Ctx[base + ni * 16 + lc] = f2bf(oacc[mi][ni][r] * inv);
        }
}

// ---------------- LayerNorm over 768, one block per row ----------------
__global__ __launch_bounds__(256) void ln_kernel(const float* __restrict__ in,
                                                 const float* __restrict__ g,
                                                 const float* __restrict__ bb,
                                                 u16* __restrict__ out_bf,
                                                 float* __restrict__ out_f) {
    const int row = blockIdx.x, tid = threadIdx.x;
    const float* x = in + (size_t)row * DD;
    float v0 = x[tid], v1 = x[tid + 256], v2 = x[tid + 512];
    float s = v0 + v1 + v2;
    float q = v0 * v0 + v1 * v1 + v2 * v2;
#pragma unroll
    for (int o = 1; o < 64; o <<= 1) {
        s += __shfl_xor(s, o);
        q += __shfl_xor(q, o);
    }
    __shared__ float rs[4], rq[4];
    int wave = tid >> 6;
    if ((tid & 63) == 0) { rs[wave] = s; rq[wave] = q; }
    __syncthreads();
    s = rs[0] + rs[1] + rs[2] + rs[3];
    q = rq[0] + rq[1] + rq[2] + rq[3];
    float mu = s * (1.0f / DD);
    float var = q * (1.0f / DD) - mu * mu;
    float rstd = rsqrtf(var + 1e-5f);
#pragma unroll
    for (int j = 0; j < 3; ++j) {
        int col = tid + j * 256;
        float v = (j == 0 ? v0 : (j == 1 ? v1 : v2));
        float y = (v - mu) * rstd * g[col] + bb[col];
        if (out_bf) out_bf[(size_t)row * DD + col] = f2bf(y);
        if (out_f) out_f[(size_t)row * DD + col] = y;
    }
}

extern "C" void kernel_launch(void* const* d_in, const int* in_sizes, int n_in,
                              void* d_out, int out_size, void* d_ws, size_t ws_size,
                              hipStream_t stream) {
    const float* X    = (const float*)d_in[0];
    const int*   mask = (const int*)d_in[1];
    const float* Wq   = (const float*)d_in[2];
    const float* Wk   = (const float*)d_in[3];
    const float* Wv   = (const float*)d_in[4];
    const float* Wo   = (const float*)d_in[5];
    const float* W1   = (const float*)d_in[6];
    const float* W2   = (const float*)d_in[7];
    const float* ln_g = (const float*)d_in[8];
    const float* ln_b = (const float*)d_in[9];
    float* out = (float*)d_out;

    char* ws = (char*)d_ws;
    size_t off = 0;
    auto alloc = [&](size_t bytes) {
        void* p = ws + off;
        off += (bytes + 255) & ~(size_t)255;
        return p;
    };
    u16*   Xbf   = (u16*)alloc((size_t)ROWS * DD * 2);       // reused as Ctx
    u16*   Wqkvb = (u16*)alloc((size_t)3 * DD * DD * 2);
    u16*   Wob   = (u16*)alloc((size_t)DD * DD * 2);
    u16*   W1b   = (u16*)alloc((size_t)4 * DD * DD * 2);
    u16*   W2b   = (u16*)alloc((size_t)4 * DD * DD * 2);
    float* mbias = (float*)alloc((size_t)NB * SS * 4);
    u16*   Qb    = (u16*)alloc((size_t)ROWS * DD * 2);       // Qb..Vtb reused as Gb
    u16*   Kb    = (u16*)alloc((size_t)ROWS * DD * 2);
    u16*   Vb    = (u16*)alloc((size_t)ROWS * DD * 2);
    u16*   Vtb   = (u16*)alloc((size_t)ROWS * DD * 2);
    float* resid = (float*)alloc((size_t)ROWS * DD * 4);     // reused as h2
    u16*   n1b   = (u16*)alloc((size_t)ROWS * DD * 2);
    u16*   Gb    = Qb;          // 8192*3072*2 = 4 * (8192*768*2) = Qb..Vtb
    u16*   Ctxb  = Xbf;
    float* h2    = resid;

    // fused casts + mask bias (13064 blocks)
    prep_kernel<<<dim3(13064), dim3(256), 0, stream>>>(
        X, Wq, Wk, Wv, Wo, W1, W2, mask,
        Xbf, Wqkvb, Wob, W1b, W2b, mbias);

    // QKV projection: [8192, 2304]
    gemm_bt<0, 128><<<dim3(3 * DD / 128, ROWS / 128), dim3(256), 0, stream>>>(
        Xbf, Wqkvb, ROWS, 3 * DD, DD, nullptr, nullptr, Qb, Kb, Vb);

    transpose_v<<<dim3(SS / 32, HD / 32, NB * HH), dim3(256), 0, stream>>>(Vb, Vtb);

    attn_kernel<<<dim3(SS / 128, NB * HH), dim3(256), 0, stream>>>(Qb, Kb, Vtb, mbias, Ctxb);

    // O projection + residual: resid = x + ctx @ Wo^T
    gemm_bt<2, 64><<<dim3(DD / 64, ROWS / 128), dim3(256), 0, stream>>>(
        Ctxb, Wob, ROWS, DD, DD, resid, X, nullptr, nullptr, nullptr);

    ln_kernel<<<dim3(ROWS), dim3(256), 0, stream>>>(resid, ln_g, ln_b, n1b, nullptr);

    // FFN1 + GELU: [8192, 3072] bf16
    gemm_bt<1, 128><<<dim3(4 * DD / 128, ROWS / 128), dim3(256), 0, stream>>>(
        n1b, W1b, ROWS, 4 * DD, DD, Gb, nullptr, nullptr, nullptr, nullptr);

    // FFN2 + residual: h2 = n1 + g @ W2^T
    gemm_bt<3, 64><<<dim3(DD / 64, ROWS / 128), dim3(256), 0, stream>>>(
        Gb, W2b, ROWS, DD, 4 * DD, h2, n1b, nullptr, nullptr, nullptr);

    ln_kernel<<<dim3(ROWS), dim3(256), 0, stream>>>(h2, ln_g, ln_b, nullptr, out);
}

// Round 8
// 396.766 us; speedup vs baseline: 1.3759x; 1.0375x over previous
//
#include <hip/hip_runtime.h>
#include <math.h>

typedef unsigned short u16;
typedef unsigned int u32;
typedef __bf16 bf16x8 __attribute__((ext_vector_type(8)));
typedef float f32x4 __attribute__((ext_vector_type(4)));

#define NB 4
#define SS 2048
#define DD 768
#define HH 12
#define HD 64
#define ROWS (NB*SS)   // 8192

__device__ __forceinline__ u16 f2bf(float f) {
    union { float f; unsigned u; } v; v.f = f;
    unsigned r = v.u + 0x7fffu + ((v.u >> 16) & 1u);
    return (u16)(r >> 16);
}
__device__ __forceinline__ u32 fas(float f) { union { float f; u32 u; } v; v.f = f; return v.u; }

__device__ __forceinline__ void gl_lds16(const void* g, void* l) {
    __builtin_amdgcn_global_load_lds((__attribute__((address_space(1))) void*)(g),
                                     (__attribute__((address_space(3))) void*)(l),
                                     16, 0, 0);
}

// ---------------- fused prep: all f32->bf16 casts + mask bias ----------------
__global__ __launch_bounds__(256) void prep_kernel(
        const float* __restrict__ X, const float* __restrict__ Wq,
        const float* __restrict__ Wk, const float* __restrict__ Wv,
        const float* __restrict__ Wo, const float* __restrict__ W1,
        const float* __restrict__ W2, const int* __restrict__ mask,
        u16* __restrict__ Xb, u16* __restrict__ Wqkvb, u16* __restrict__ Wob,
        u16* __restrict__ W1b, u16* __restrict__ W2b, float* __restrict__ mb) {
    const int blk = blockIdx.x, tid = threadIdx.x;
    const float* src; u16* dst; int idx;
    if (blk < 6144)       { src = X;  dst = Xb;               idx = blk * 1024 + tid * 4; }
    else if (blk < 6720)  { src = Wq; dst = Wqkvb;            idx = (blk - 6144) * 1024 + tid * 4; }
    else if (blk < 7296)  { src = Wk; dst = Wqkvb + DD * DD;  idx = (blk - 6720) * 1024 + tid * 4; }
    else if (blk < 7872)  { src = Wv; dst = Wqkvb + 2*DD*DD;  idx = (blk - 7296) * 1024 + tid * 4; }
    else if (blk < 8448)  { src = Wo; dst = Wob;              idx = (blk - 7872) * 1024 + tid * 4; }
    else if (blk < 10752) { src = W1; dst = W1b;              idx = (blk - 8448) * 1024 + tid * 4; }
    else if (blk < 13056) { src = W2; dst = W2b;              idx = (blk - 10752) * 1024 + tid * 4; }
    else {
        int i = (blk - 13056) * 1024 + tid * 4;
        float4 o;
        o.x = mask[i]     == 0 ? -1e30f : 0.0f;
        o.y = mask[i + 1] == 0 ? -1e30f : 0.0f;
        o.z = mask[i + 2] == 0 ? -1e30f : 0.0f;
        o.w = mask[i + 3] == 0 ? -1e30f : 0.0f;
        *(float4*)&mb[i] = o;
        return;
    }
    float4 v = *(const float4*)&src[idx];
    ushort4 o;
    o.x = f2bf(v.x); o.y = f2bf(v.y); o.z = f2bf(v.z); o.w = f2bf(v.w);
    *(ushort4*)&dst[idx] = o;
}

// ---------------- GEMM: C[M,N] = A[M,K] (bf16) * B[N,K]^T (bf16) ----------------
// 128xBN tile, BK=64, 4 waves. Chunk-swizzled LDS (phys = c ^ (row&7)).
// EPI 0: scatter to Q/K/V [B,H,S,D] bf16
// EPI 1: tanh-form GELU (raw v_exp/v_rcp; |err| vs exact <= ~3e-4) -> bf16
// EPI 2: + auxF (f32) -> f32 ; EPI 3: + auxB (bf16) -> f32
template <int EPI, int BN>
__global__ __launch_bounds__(256) void gemm_bt(const u16* __restrict__ A,
                                               const u16* __restrict__ B,
                                               int M, int N, int K,
                                               void* __restrict__ out,
                                               const void* __restrict__ aux,
                                               u16* __restrict__ Qb,
                                               u16* __restrict__ Kb,
                                               u16* __restrict__ Vb) {
    __shared__ __align__(16) u16 lA[128 * 64];
    __shared__ __align__(16) u16 lB[BN * 64];
    constexpr int MI = (BN == 128) ? 4 : 2;
    const int tid = threadIdx.x;
    const int lane = tid & 63, wave = tid >> 6;
    const int quad = lane >> 4, lc = lane & 15;
    const int m0 = blockIdx.y * 128, n0 = blockIdx.x * BN;
    const int wrow = (BN == 128) ? (wave >> 1) * 64 : wave * 32;
    const int wcol = (BN == 128) ? (wave & 1) * 64 : 0;
    const int swz = lc & 7;

    f32x4 acc[MI][4] = {};

    for (int kb = 0; kb < K; kb += 64) {
        __syncthreads();
#pragma unroll
        for (int p0 = 0; p0 < 1024; p0 += 256) {
            int p = p0 + tid, row = p >> 3, cl = (p & 7) ^ (row & 7);
            gl_lds16(A + (size_t)(m0 + row) * K + kb + cl * 8, &lA[(size_t)(p0 + wave * 64) * 8]);
        }
#pragma unroll
        for (int p0 = 0; p0 < BN * 8; p0 += 256) {
            int p = p0 + tid, row = p >> 3, cl = (p & 7) ^ (row & 7);
            gl_lds16(B + (size_t)(n0 + row) * K + kb + cl * 8, &lB[(size_t)(p0 + wave * 64) * 8]);
        }
        __syncthreads();
#pragma unroll
        for (int k2 = 0; k2 < 2; ++k2) {
            bf16x8 af[MI], bfr[4];
#pragma unroll
            for (int t = 0; t < MI; ++t)
                af[t] = *(const bf16x8*)&lA[(wrow + t * 16 + lc) * 64 + ((quad + k2 * 4) ^ swz) * 8];
#pragma unroll
            for (int t = 0; t < 4; ++t)
                bfr[t] = *(const bf16x8*)&lB[(wcol + t * 16 + lc) * 64 + ((quad + k2 * 4) ^ swz) * 8];
#pragma unroll
            for (int mi = 0; mi < MI; ++mi)
#pragma unroll
                for (int ni = 0; ni < 4; ++ni)
                    acc[mi][ni] = __builtin_amdgcn_mfma_f32_16x16x32_bf16(af[mi], bfr[ni],
                                                                         acc[mi][ni], 0, 0, 0);
        }
    }

#pragma unroll
    for (int mi = 0; mi < MI; ++mi) {
#pragma unroll
        for (int r = 0; r < 4; ++r) {
            int m = m0 + wrow + mi * 16 + quad * 4 + r;
#pragma unroll
            for (int ni = 0; ni < 4; ++ni) {
                int n = n0 + wcol + ni * 16 + lc;
                float v = acc[mi][ni][r];
                if constexpr (EPI == 0) {
                    int b = m >> 11, s = m & 2047;
                    int which = n / DD, rem = n - which * DD;
                    int h = rem >> 6, d = rem & 63;
                    u16* dst = which == 0 ? Qb : (which == 1 ? Kb : Vb);
                    dst[((((size_t)b * HH + h) * SS + s) << 6) + d] = f2bf(v);
                } else if constexpr (EPI == 1) {
                    // gelu_tanh(v) = v * sigmoid(2*0.79788456*(v + 0.044715 v^3))
                    float u = v * fmaf(v * v, 0.035677408f, 0.7978845608f);
                    float e = __builtin_amdgcn_exp2f(u * 2.885390082f);  // e^{2u}
                    float g = v - v * __builtin_amdgcn_rcpf(e + 1.0f);
                    ((u16*)out)[(size_t)m * N + n] = f2bf(g);
                } else if constexpr (EPI == 2) {
                    ((float*)out)[(size_t)m * N + n] =
                        v + ((const float*)aux)[(size_t)m * N + n];
                } else {
                    ((float*)out)[(size_t)m * N + n] =
                        v + (float)(((const __bf16*)aux)[(size_t)m * N + n]);
                }
            }
        }
    }
}

// ---------------- V transpose: [B,H,S,D] -> [B,H,D,S] (bf16) ----------------
__global__ __launch_bounds__(256) void transpose_v(const u16* __restrict__ V,
                                                   u16* __restrict__ Vt) {
    __shared__ u16 t[32][33];
    int bh = blockIdx.z;
    int s0 = blockIdx.x * 32, d0 = blockIdx.y * 32;
    const u16* vb = V + (size_t)bh * SS * HD;
    u16* vtb = Vt + (size_t)bh * HD * SS;
    int tx = threadIdx.x & 31, ty = threadIdx.x >> 5;
#pragma unroll
    for (int i = 0; i < 32; i += 8) t[ty + i][tx] = vb[(size_t)(s0 + ty + i) * HD + d0 + tx];
    __syncthreads();
#pragma unroll
    for (int i = 0; i < 32; i += 8) vtb[(size_t)(d0 + ty + i) * SS + s0 + tx] = t[tx][ty + i];
}

// ---------------- flash attention (S^T, dbuf staging, raw v_exp) ----------------
// 1D grid 768, XCD-swizzled: id = qb*48 + bh  =>  same-bh q-blocks share
// id mod 8 (48 % 8 == 0), i.e. one XCD's L2 holds that bh's K/V (512 KB;
// 6 bh/XCD = 3 MB < 4 MB). Round-7 FETCH was 104.6 MB vs ~38 MB compulsory
// because round-robin dispatch duplicated K/V across all 8 XCD L2s.
__global__ __launch_bounds__(256) void attn_kernel(const u16* __restrict__ Q,
                                                   const u16* __restrict__ K,
                                                   const u16* __restrict__ Vt,
                                                   const float* __restrict__ maskbias,
                                                   u16* __restrict__ Ctx) {
    __shared__ __align__(16) u16 lK[2][64 * 64];
    __shared__ __align__(16) u16 lV[2][64 * 64];   // [d][key]
    __shared__ __align__(16) u16 lP[4][32 * 72];
    const int tid = threadIdx.x, lane = tid & 63, wave = tid >> 6;
    const int quad = lane >> 4, lc = lane & 15;
    const int bh = blockIdx.x % (NB * HH);
    const int b = bh / HH, h = bh - b * HH;
    const int q0 = (blockIdx.x / (NB * HH)) * 128;
    const u16* Qg = Q + ((size_t)bh * SS + q0 + wave * 32) * HD;
    const u16* Kg = K + (size_t)bh * SS * HD;
    const u16* Vg = Vt + (size_t)bh * HD * SS;
    const float* mbg = maskbias + b * SS;
    const int sw = lc & 7;

    const int srow = tid >> 3, scl = (tid & 7) ^ (srow & 7);
    const int srow2 = (256 + tid) >> 3, scl2 = (tid & 7) ^ (srow2 & 7);

    // Q fragments (B-operand): n = q = mi*16+lc, k = k2*32+quad*8+j
    bf16x8 qf[2][2];
#pragma unroll
    for (int mi = 0; mi < 2; ++mi)
#pragma unroll
        for (int k2 = 0; k2 < 2; ++k2)
            qf[mi][k2] = *(const bf16x8*)(Qg + (size_t)(mi * 16 + lc) * HD + k2 * 32 + quad * 8);

    bf16x8 onesf;
#pragma unroll
    for (int i = 0; i < 8; ++i) onesf[i] = (__bf16)1.0f;

    f32x4 oacc[2][4] = {};
    f32x4 lsum[2] = {};

    // stage tile 0 into buffer 0
    {
        gl_lds16(Kg + (size_t)srow * HD + scl * 8,        &lK[0][(size_t)(wave * 64) * 8]);
        gl_lds16(Vg + (size_t)srow * SS + scl * 8,        &lV[0][(size_t)(wave * 64) * 8]);
        gl_lds16(Kg + (size_t)srow2 * HD + scl2 * 8,      &lK[0][(size_t)(256 + wave * 64) * 8]);
        gl_lds16(Vg + (size_t)srow2 * SS + scl2 * 8,      &lV[0][(size_t)(256 + wave * 64) * 8]);
    }

    for (int j0 = 0; j0 < SS; j0 += 64) {
        const int cur = (j0 >> 6) & 1;
        __syncthreads();   // stage(j0) complete; drain overlapped with prior tile's compute
        if (j0 + 64 < SS) {
            const int nxt = cur ^ 1;
            gl_lds16(Kg + (size_t)(j0 + 64 + srow) * HD + scl * 8,   &lK[nxt][(size_t)(wave * 64) * 8]);
            gl_lds16(Vg + (size_t)srow * SS + j0 + 64 + scl * 8,     &lV[nxt][(size_t)(wave * 64) * 8]);
            gl_lds16(Kg + (size_t)(j0 + 64 + srow2) * HD + scl2 * 8, &lK[nxt][(size_t)(256 + wave * 64) * 8]);
            gl_lds16(Vg + (size_t)srow2 * SS + j0 + 64 + scl2 * 8,   &lV[nxt][(size_t)(256 + wave * 64) * 8]);
        }

        // S^T = K Q^T: per-lane q = mi*16+lc, key = ni*16+quad*4+r
        f32x4 sacc[4][2] = {};
#pragma unroll
        for (int k2 = 0; k2 < 2; ++k2)
#pragma unroll
            for (int ni = 0; ni < 4; ++ni) {
                bf16x8 kf = *(const bf16x8*)&lK[cur][(ni * 16 + lc) * 64 + ((quad + k2 * 4) ^ sw) * 8];
                sacc[ni][0] = __builtin_amdgcn_mfma_f32_16x16x32_bf16(kf, qf[0][k2], sacc[ni][0], 0, 0, 0);
                sacc[ni][1] = __builtin_amdgcn_mfma_f32_16x16x32_bf16(kf, qf[1][k2], sacc[ni][1], 0, 0, 0);
            }

        // p = exp2(s*log2e/8 + mb[key]) via raw v_exp_f32
#pragma unroll
        for (int ni = 0; ni < 4; ++ni) {
            f32x4 mbv = *(const f32x4*)(mbg + j0 + ni * 16 + quad * 4);
#pragma unroll
            for (int mi = 0; mi < 2; ++mi) {
#pragma unroll
                for (int r = 0; r < 4; ++r)
                    sacc[ni][mi][r] = __builtin_amdgcn_exp2f(fmaf(sacc[ni][mi][r], 0.180336880f, mbv[r]));
                u32 w0 = __builtin_amdgcn_perm(fas(sacc[ni][mi][1]), fas(sacc[ni][mi][0]), 0x07060302);
                u32 w1 = __builtin_amdgcn_perm(fas(sacc[ni][mi][3]), fas(sacc[ni][mi][2]), 0x07060302);
                *(uint2*)&lP[wave][(mi * 16 + lc) * 72 + ni * 16 + quad * 4] = make_uint2(w0, w1);
            }
        }

        // O += P V ; l += P * ones  (lP wave-private: no barrier)
#pragma unroll
        for (int k2 = 0; k2 < 2; ++k2) {
            bf16x8 pf0 = *(const bf16x8*)&lP[wave][(size_t)lc * 72 + k2 * 32 + quad * 8];
            bf16x8 pf1 = *(const bf16x8*)&lP[wave][(size_t)(16 + lc) * 72 + k2 * 32 + quad * 8];
            lsum[0] = __builtin_amdgcn_mfma_f32_16x16x32_bf16(pf0, onesf, lsum[0], 0, 0, 0);
            lsum[1] = __builtin_amdgcn_mfma_f32_16x16x32_bf16(pf1, onesf, lsum[1], 0, 0, 0);
#pragma unroll
            for (int ni = 0; ni < 4; ++ni) {
                bf16x8 vf = *(const bf16x8*)&lV[cur][(ni * 16 + lc) * 64 + ((quad + k2 * 4) ^ sw) * 8];
                oacc[0][ni] = __builtin_amdgcn_mfma_f32_16x16x32_bf16(pf0, vf, oacc[0][ni], 0, 0, 0);
                oacc[1][ni] = __builtin_amdgcn_mfma_f32_16x16x32_bf16(pf1, vf, oacc[1][ni], 0, 0, 0);
            }
        }
    }

    // epilogue: normalize and store (lsum in C-layout alongside oacc)
#pragma unroll
    for (int mi = 0; mi < 2; ++mi)
#pragma unroll
        for (int r = 0; r < 4; ++r) {
            float inv = 1.0f / lsum[mi][r];
            int s = q0 + wave * 32 + mi * 16 + quad * 4 + r;
            size_t base = ((size_t)(b * SS + s)) * DD + h * HD;
#pragma unroll
            for (int ni = 0; ni < 4; ++ni)
                Ctx[base + ni * 16 + lc] = f2bf(oacc[mi][ni][r] * inv);
        }
}

// ---------------- LayerNorm over 768, one block per row ----------------
__global__ __launch_bounds__(256) void ln_kernel(const float* __restrict__ in,
                                                 const float* __restrict__ g,
                                                 const float* __restrict__ bb,
                                                 u16* __restrict__ out_bf,
                                                 float* __restrict__ out_f) {
    const int row = blockIdx.x, tid = threadIdx.x;
    const float* x = in + (size_t)row * DD;
    float v0 = x[tid], v1 = x[tid + 256], v2 = x[tid + 512];
    float s = v0 + v1 + v2;
    float q = v0 * v0 + v1 * v1 + v2 * v2;
#pragma unroll
    for (int o = 1; o < 64; o <<= 1) {
        s += __shfl_xor(s, o);
        q += __shfl_xor(q, o);
    }
    __shared__ float rs[4], rq[4];
    int wave = tid >> 6;
    if ((tid & 63) == 0) { rs[wave] = s; rq[wave] = q; }
    __syncthreads();
    s = rs[0] + rs[1] + rs[2] + rs[3];
    q = rq[0] + rq[1] + rq[2] + rq[3];
    float mu = s * (1.0f / DD);
    float var = q * (1.0f / DD) - mu * mu;
    float rstd = rsqrtf(var + 1e-5f);
#pragma unroll
    for (int j = 0; j < 3; ++j) {
        int col = tid + j * 256;
        float v = (j == 0 ? v0 : (j == 1 ? v1 : v2));
        float y = (v - mu) * rstd * g[col] + bb[col];
        if (out_bf) out_bf[(size_t)row * DD + col] = f2bf(y);
        if (out_f) out_f[(size_t)row * DD + col] = y;
    }
}

extern "C" void kernel_launch(void* const* d_in, const int* in_sizes, int n_in,
                              void* d_out, int out_size, void* d_ws, size_t ws_size,
                              hipStream_t stream) {
    const float* X    = (const float*)d_in[0];
    const int*   mask = (const int*)d_in[1];
    const float* Wq   = (const float*)d_in[2];
    const float* Wk   = (const float*)d_in[3];
    const float* Wv   = (const float*)d_in[4];
    const float* Wo   = (const float*)d_in[5];
    const float* W1   = (const float*)d_in[6];
    const float* W2   = (const float*)d_in[7];
    const float* ln_g = (const float*)d_in[8];
    const float* ln_b = (const float*)d_in[9];
    float* out = (float*)d_out;

    char* ws = (char*)d_ws;
    size_t off = 0;
    auto alloc = [&](size_t bytes) {
        void* p = ws + off;
        off += (bytes + 255) & ~(size_t)255;
        return p;
    };
    u16*   Xbf   = (u16*)alloc((size_t)ROWS * DD * 2);       // reused as Ctx
    u16*   Wqkvb = (u16*)alloc((size_t)3 * DD * DD * 2);
    u16*   Wob   = (u16*)alloc((size_t)DD * DD * 2);
    u16*   W1b   = (u16*)alloc((size_t)4 * DD * DD * 2);
    u16*   W2b   = (u16*)alloc((size_t)4 * DD * DD * 2);
    float* mbias = (float*)alloc((size_t)NB * SS * 4);
    u16*   Qb    = (u16*)alloc((size_t)ROWS * DD * 2);       // Qb..Vtb reused as Gb
    u16*   Kb    = (u16*)alloc((size_t)ROWS * DD * 2);
    u16*   Vb    = (u16*)alloc((size_t)ROWS * DD * 2);
    u16*   Vtb   = (u16*)alloc((size_t)ROWS * DD * 2);
    float* resid = (float*)alloc((size_t)ROWS * DD * 4);     // reused as h2
    u16*   n1b   = (u16*)alloc((size_t)ROWS * DD * 2);
    u16*   Gb    = Qb;          // 8192*3072*2 = 4 * (8192*768*2) = Qb..Vtb
    u16*   Ctxb  = Xbf;
    float* h2    = resid;

    // fused casts + mask bias (13064 blocks)
    prep_kernel<<<dim3(13064), dim3(256), 0, stream>>>(
        X, Wq, Wk, Wv, Wo, W1, W2, mask,
        Xbf, Wqkvb, Wob, W1b, W2b, mbias);

    // QKV projection: [8192, 2304]
    gemm_bt<0, 128><<<dim3(3 * DD / 128, ROWS / 128), dim3(256), 0, stream>>>(
        Xbf, Wqkvb, ROWS, 3 * DD, DD, nullptr, nullptr, Qb, Kb, Vb);

    transpose_v<<<dim3(SS / 32, HD / 32, NB * HH), dim3(256), 0, stream>>>(Vb, Vtb);

    // 1D XCD-swizzled grid: id = qb*48 + bh
    attn_kernel<<<dim3((SS / 128) * (NB * HH)), dim3(256), 0, stream>>>(
        Qb, Kb, Vtb, mbias, Ctxb);

    // O projection + residual: resid = x + ctx @ Wo^T
    gemm_bt<2, 64><<<dim3(DD / 64, ROWS / 128), dim3(256), 0, stream>>>(
        Ctxb, Wob, ROWS, DD, DD, resid, X, nullptr, nullptr, nullptr);

    ln_kernel<<<dim3(ROWS), dim3(256), 0, stream>>>(resid, ln_g, ln_b, n1b, nullptr);

    // FFN1 + GELU(tanh-form): [8192, 3072] bf16
    gemm_bt<1, 128><<<dim3(4 * DD / 128, ROWS / 128), dim3(256), 0, stream>>>(
        n1b, W1b, ROWS, 4 * DD, DD, Gb, nullptr, nullptr, nullptr, nullptr);

    // FFN2 + residual: h2 = n1 + g @ W2^T
    gemm_bt<3, 64><<<dim3(DD / 64, ROWS / 128), dim3(256), 0, stream>>>(
        Gb, W2b, ROWS, DD, 4 * DD, h2, n1b, nullptr, nullptr, nullptr);

    ln_kernel<<<dim3(ROWS), dim3(256), 0, stream>>>(h2, ln_g, ln_b, nullptr, out);
}

// Round 9
// 367.067 us; speedup vs baseline: 1.4872x; 1.0809x over previous
//
#include <hip/hip_runtime.h>
#include <math.h>

typedef unsigned short u16;
typedef unsigned int u32;
typedef __bf16 bf16x8 __attribute__((ext_vector_type(8)));
typedef float f32x4 __attribute__((ext_vector_type(4)));

#define NB 4
#define SS 2048
#define DD 768
#define HH 12
#define HD 64
#define ROWS (NB*SS)   // 8192

__device__ __forceinline__ u16 f2bf(float f) {
    union { float f; unsigned u; } v; v.f = f;
    unsigned r = v.u + 0x7fffu + ((v.u >> 16) & 1u);
    return (u16)(r >> 16);
}
__device__ __forceinline__ u32 fas(float f) { union { float f; u32 u; } v; v.f = f; return v.u; }

__device__ __forceinline__ void gl_lds16(const void* g, void* l) {
    __builtin_amdgcn_global_load_lds((__attribute__((address_space(1))) void*)(g),
                                     (__attribute__((address_space(3))) void*)(l),
                                     16, 0, 0);
}

// ---------------- fused prep: all f32->bf16 casts + mask bias ----------------
__global__ __launch_bounds__(256) void prep_kernel(
        const float* __restrict__ X, const float* __restrict__ Wq,
        const float* __restrict__ Wk, const float* __restrict__ Wv,
        const float* __restrict__ Wo, const float* __restrict__ W1,
        const float* __restrict__ W2, const int* __restrict__ mask,
        u16* __restrict__ Xb, u16* __restrict__ Wqkvb, u16* __restrict__ Wob,
        u16* __restrict__ W1b, u16* __restrict__ W2b, float* __restrict__ mb) {
    const int blk = blockIdx.x, tid = threadIdx.x;
    const float* src; u16* dst; int idx;
    if (blk < 6144)       { src = X;  dst = Xb;               idx = blk * 1024 + tid * 4; }
    else if (blk < 6720)  { src = Wq; dst = Wqkvb;            idx = (blk - 6144) * 1024 + tid * 4; }
    else if (blk < 7296)  { src = Wk; dst = Wqkvb + DD * DD;  idx = (blk - 6720) * 1024 + tid * 4; }
    else if (blk < 7872)  { src = Wv; dst = Wqkvb + 2*DD*DD;  idx = (blk - 7296) * 1024 + tid * 4; }
    else if (blk < 8448)  { src = Wo; dst = Wob;              idx = (blk - 7872) * 1024 + tid * 4; }
    else if (blk < 10752) { src = W1; dst = W1b;              idx = (blk - 8448) * 1024 + tid * 4; }
    else if (blk < 13056) { src = W2; dst = W2b;              idx = (blk - 10752) * 1024 + tid * 4; }
    else {
        int i = (blk - 13056) * 1024 + tid * 4;
        float4 o;
        o.x = mask[i]     == 0 ? -1e30f : 0.0f;
        o.y = mask[i + 1] == 0 ? -1e30f : 0.0f;
        o.z = mask[i + 2] == 0 ? -1e30f : 0.0f;
        o.w = mask[i + 3] == 0 ? -1e30f : 0.0f;
        *(float4*)&mb[i] = o;
        return;
    }
    float4 v = *(const float4*)&src[idx];
    ushort4 o;
    o.x = f2bf(v.x); o.y = f2bf(v.y); o.z = f2bf(v.z); o.w = f2bf(v.w);
    *(ushort4*)&dst[idx] = o;
}

// ---------------- GEMM: C[M,N] = A[M,K] (bf16) * B[N,K]^T (bf16) ----------------
// 128xBN tile, BK=64, 4 waves, chunk-swizzled LDS (phys = c ^ (row&7)).
// 1D grid, XCD-slab mapping: xcd = id&7 owns m-blocks [xcd*8, xcd*8+8) x all n.
// Co-resident blocks on an XCD stream K together, so live A/B K-slices stay
// in that XCD's L2 (round-8 default mapping re-read A from L3 ~12x on FFN2).
// EPI 0: scatter Q/K/V [B,H,S,D] | 1: tanh-GELU bf16 | 2: +auxF f32 | 3: +auxB f32
template <int EPI, int BN>
__global__ __launch_bounds__(256) void gemm_bt(const u16* __restrict__ A,
                                               const u16* __restrict__ B,
                                               int M, int N, int K,
                                               void* __restrict__ out,
                                               const void* __restrict__ aux,
                                               u16* __restrict__ Qb,
                                               u16* __restrict__ Kb,
                                               u16* __restrict__ Vb) {
    __shared__ __align__(16) u16 lA[128 * 64];
    __shared__ __align__(16) u16 lB[BN * 64];
    constexpr int MI = (BN == 128) ? 4 : 2;
    const int tid = threadIdx.x;
    const int lane = tid & 63, wave = tid >> 6;
    const int quad = lane >> 4, lc = lane & 15;
    const int xcd = blockIdx.x & 7, loc = blockIdx.x >> 3;
    const int mb = xcd * 8 + (loc & 7), nb = loc >> 3;   // M=8192 fixed: 64 m-blocks
    const int m0 = mb * 128, n0 = nb * BN;
    const int wrow = (BN == 128) ? (wave >> 1) * 64 : wave * 32;
    const int wcol = (BN == 128) ? (wave & 1) * 64 : 0;
    const int swz = lc & 7;

    f32x4 acc[MI][4] = {};

    for (int kb = 0; kb < K; kb += 64) {
        __syncthreads();
#pragma unroll
        for (int p0 = 0; p0 < 1024; p0 += 256) {
            int p = p0 + tid, row = p >> 3, cl = (p & 7) ^ (row & 7);
            gl_lds16(A + (size_t)(m0 + row) * K + kb + cl * 8, &lA[(size_t)(p0 + wave * 64) * 8]);
        }
#pragma unroll
        for (int p0 = 0; p0 < BN * 8; p0 += 256) {
            int p = p0 + tid, row = p >> 3, cl = (p & 7) ^ (row & 7);
            gl_lds16(B + (size_t)(n0 + row) * K + kb + cl * 8, &lB[(size_t)(p0 + wave * 64) * 8]);
        }
        __syncthreads();
#pragma unroll
        for (int k2 = 0; k2 < 2; ++k2) {
            bf16x8 af[MI], bfr[4];
#pragma unroll
            for (int t = 0; t < MI; ++t)
                af[t] = *(const bf16x8*)&lA[(wrow + t * 16 + lc) * 64 + ((quad + k2 * 4) ^ swz) * 8];
#pragma unroll
            for (int t = 0; t < 4; ++t)
                bfr[t] = *(const bf16x8*)&lB[(wcol + t * 16 + lc) * 64 + ((quad + k2 * 4) ^ swz) * 8];
#pragma unroll
            for (int mi = 0; mi < MI; ++mi)
#pragma unroll
                for (int ni = 0; ni < 4; ++ni)
                    acc[mi][ni] = __builtin_amdgcn_mfma_f32_16x16x32_bf16(af[mi], bfr[ni],
                                                                         acc[mi][ni], 0, 0, 0);
        }
    }

#pragma unroll
    for (int mi = 0; mi < MI; ++mi) {
#pragma unroll
        for (int r = 0; r < 4; ++r) {
            int m = m0 + wrow + mi * 16 + quad * 4 + r;
#pragma unroll
            for (int ni = 0; ni < 4; ++ni) {
                int n = n0 + wcol + ni * 16 + lc;
                float v = acc[mi][ni][r];
                if constexpr (EPI == 0) {
                    int b = m >> 11, s = m & 2047;
                    int which = n / DD, rem = n - which * DD;
                    int h = rem >> 6, d = rem & 63;
                    u16* dst = which == 0 ? Qb : (which == 1 ? Kb : Vb);
                    dst[((((size_t)b * HH + h) * SS + s) << 6) + d] = f2bf(v);
                } else if constexpr (EPI == 1) {
                    // gelu_tanh(v) = v * sigmoid(2*0.79788456*(v + 0.044715 v^3))
                    float u = v * fmaf(v * v, 0.035677408f, 0.7978845608f);
                    float e = __builtin_amdgcn_exp2f(u * 2.885390082f);  // e^{2u}
                    float g = v - v * __builtin_amdgcn_rcpf(e + 1.0f);
                    ((u16*)out)[(size_t)m * N + n] = f2bf(g);
                } else if constexpr (EPI == 2) {
                    ((float*)out)[(size_t)m * N + n] =
                        v + ((const float*)aux)[(size_t)m * N + n];
                } else {
                    ((float*)out)[(size_t)m * N + n] =
                        v + (float)(((const __bf16*)aux)[(size_t)m * N + n]);
                }
            }
        }
    }
}

// ---------------- V transpose: [B,H,S,D] -> [B,H,D,S] (bf16) ----------------
__global__ __launch_bounds__(256) void transpose_v(const u16* __restrict__ V,
                                                   u16* __restrict__ Vt) {
    __shared__ u16 t[32][33];
    int bh = blockIdx.z;
    int s0 = blockIdx.x * 32, d0 = blockIdx.y * 32;
    const u16* vb = V + (size_t)bh * SS * HD;
    u16* vtb = Vt + (size_t)bh * HD * SS;
    int tx = threadIdx.x & 31, ty = threadIdx.x >> 5;
#pragma unroll
    for (int i = 0; i < 32; i += 8) t[ty + i][tx] = vb[(size_t)(s0 + ty + i) * HD + d0 + tx];
    __syncthreads();
#pragma unroll
    for (int i = 0; i < 32; i += 8) vtb[(size_t)(d0 + ty + i) * SS + s0 + tx] = t[tx][ty + i];
}

// ---------------- flash attention (S^T, single-buffer, 4 blocks/CU) ----------------
// 1D grid 768, XCD-swizzled (id = qb*48 + bh). Single K/V buffer: LDS
// 34 KB -> 4 blocks/CU (r6 dbuf was measured neutral; occupancy is the
// binding constraint on this issue-bound kernel, 26% at 3 blocks/CU).
__global__ __launch_bounds__(256) void attn_kernel(const u16* __restrict__ Q,
                                                   const u16* __restrict__ K,
                                                   const u16* __restrict__ Vt,
                                                   const float* __restrict__ maskbias,
                                                   u16* __restrict__ Ctx) {
    __shared__ __align__(16) u16 lK[64 * 64];
    __shared__ __align__(16) u16 lV[64 * 64];   // [d][key]
    __shared__ __align__(16) u16 lP[4][32 * 72];
    const int tid = threadIdx.x, lane = tid & 63, wave = tid >> 6;
    const int quad = lane >> 4, lc = lane & 15;
    const int bh = blockIdx.x % (NB * HH);
    const int b = bh / HH, h = bh - b * HH;
    const int q0 = (blockIdx.x / (NB * HH)) * 128;
    const u16* Qg = Q + ((size_t)bh * SS + q0 + wave * 32) * HD;
    const u16* Kg = K + (size_t)bh * SS * HD;
    const u16* Vg = Vt + (size_t)bh * HD * SS;
    const float* mbg = maskbias + b * SS;
    const int sw = lc & 7;

    const int srow = tid >> 3, scl = (tid & 7) ^ (srow & 7);
    const int srow2 = (256 + tid) >> 3, scl2 = (tid & 7) ^ (srow2 & 7);

    // Q fragments (B-operand): n = q = mi*16+lc, k = k2*32+quad*8+j
    bf16x8 qf[2][2];
#pragma unroll
    for (int mi = 0; mi < 2; ++mi)
#pragma unroll
        for (int k2 = 0; k2 < 2; ++k2)
            qf[mi][k2] = *(const bf16x8*)(Qg + (size_t)(mi * 16 + lc) * HD + k2 * 32 + quad * 8);

    bf16x8 onesf;
#pragma unroll
    for (int i = 0; i < 8; ++i) onesf[i] = (__bf16)1.0f;

    f32x4 oacc[2][4] = {};
    f32x4 lsum[2] = {};

    for (int j0 = 0; j0 < SS; j0 += 64) {
        __syncthreads();
        gl_lds16(Kg + (size_t)(j0 + srow) * HD + scl * 8,   &lK[(size_t)(wave * 64) * 8]);
        gl_lds16(Vg + (size_t)srow * SS + j0 + scl * 8,     &lV[(size_t)(wave * 64) * 8]);
        gl_lds16(Kg + (size_t)(j0 + srow2) * HD + scl2 * 8, &lK[(size_t)(256 + wave * 64) * 8]);
        gl_lds16(Vg + (size_t)srow2 * SS + j0 + scl2 * 8,   &lV[(size_t)(256 + wave * 64) * 8]);
        __syncthreads();

        // S^T = K Q^T: per-lane q = mi*16+lc, key = ni*16+quad*4+r
        f32x4 sacc[4][2] = {};
#pragma unroll
        for (int k2 = 0; k2 < 2; ++k2)
#pragma unroll
            for (int ni = 0; ni < 4; ++ni) {
                bf16x8 kf = *(const bf16x8*)&lK[(ni * 16 + lc) * 64 + ((quad + k2 * 4) ^ sw) * 8];
                sacc[ni][0] = __builtin_amdgcn_mfma_f32_16x16x32_bf16(kf, qf[0][k2], sacc[ni][0], 0, 0, 0);
                sacc[ni][1] = __builtin_amdgcn_mfma_f32_16x16x32_bf16(kf, qf[1][k2], sacc[ni][1], 0, 0, 0);
            }

        // p = exp2(s*log2e/8 + mb[key]) via raw v_exp_f32
#pragma unroll
        for (int ni = 0; ni < 4; ++ni) {
            f32x4 mbv = *(const f32x4*)(mbg + j0 + ni * 16 + quad * 4);
#pragma unroll
            for (int mi = 0; mi < 2; ++mi) {
#pragma unroll
                for (int r = 0; r < 4; ++r)
                    sacc[ni][mi][r] = __builtin_amdgcn_exp2f(fmaf(sacc[ni][mi][r], 0.180336880f, mbv[r]));
                u32 w0 = __builtin_amdgcn_perm(fas(sacc[ni][mi][1]), fas(sacc[ni][mi][0]), 0x07060302);
                u32 w1 = __builtin_amdgcn_perm(fas(sacc[ni][mi][3]), fas(sacc[ni][mi][2]), 0x07060302);
                *(uint2*)&lP[wave][(mi * 16 + lc) * 72 + ni * 16 + quad * 4] = make_uint2(w0, w1);
            }
        }

        // O += P V ; l += P * ones  (lP wave-private: no barrier)
#pragma unroll
        for (int k2 = 0; k2 < 2; ++k2) {
            bf16x8 pf0 = *(const bf16x8*)&lP[wave][(size_t)lc * 72 + k2 * 32 + quad * 8];
            bf16x8 pf1 = *(const bf16x8*)&lP[wave][(size_t)(16 + lc) * 72 + k2 * 32 + quad * 8];
            lsum[0] = __builtin_amdgcn_mfma_f32_16x16x32_bf16(pf0, onesf, lsum[0], 0, 0, 0);
            lsum[1] = __builtin_amdgcn_mfma_f32_16x16x32_bf16(pf1, onesf, lsum[1], 0, 0, 0);
#pragma unroll
            for (int ni = 0; ni < 4; ++ni) {
                bf16x8 vf = *(const bf16x8*)&lV[(ni * 16 + lc) * 64 + ((quad + k2 * 4) ^ sw) * 8];
                oacc[0][ni] = __builtin_amdgcn_mfma_f32_16x16x32_bf16(pf0, vf, oacc[0][ni], 0, 0, 0);
                oacc[1][ni] = __builtin_amdgcn_mfma_f32_16x16x32_bf16(pf1, vf, oacc[1][ni], 0, 0, 0);
            }
        }
    }

    // epilogue: normalize and store (lsum in C-layout alongside oacc)
#pragma unroll
    for (int mi = 0; mi < 2; ++mi)
#pragma unroll
        for (int r = 0; r < 4; ++r) {
            float inv = 1.0f / lsum[mi][r];
            int s = q0 + wave * 32 + mi * 16 + quad * 4 + r;
            size_t base = ((size_t)(b * SS + s)) * DD + h * HD;
#pragma unroll
            for (int ni = 0; ni < 4; ++ni)
                Ctx[base + ni * 16 + lc] = f2bf(oacc[mi][ni][r] * inv);
        }
}

// ---------------- LayerNorm over 768, one block per row ----------------
__global__ __launch_bounds__(256) void ln_kernel(const float* __restrict__ in,
                                                 const float* __restrict__ g,
                                                 const float* __restrict__ bb,
                                                 u16* __restrict__ out_bf,
                                                 float* __restrict__ out_f) {
    const int row = blockIdx.x, tid = threadIdx.x;
    const float* x = in + (size_t)row * DD;
    float v0 = x[tid], v1 = x[tid + 256], v2 = x[tid + 512];
    float s = v0 + v1 + v2;
    float q = v0 * v0 + v1 * v1 + v2 * v2;
#pragma unroll
    for (int o = 1; o < 64; o <<= 1) {
        s += __shfl_xor(s, o);
        q += __shfl_xor(q, o);
    }
    __shared__ float rs[4], rq[4];
    int wave = tid >> 6;
    if ((tid & 63) == 0) { rs[wave] = s; rq[wave] = q; }
    __syncthreads();
    s = rs[0] + rs[1] + rs[2] + rs[3];
    q = rq[0] + rq[1] + rq[2] + rq[3];
    float mu = s * (1.0f / DD);
    float var = q * (1.0f / DD) - mu * mu;
    float rstd = rsqrtf(var + 1e-5f);
#pragma unroll
    for (int j = 0; j < 3; ++j) {
        int col = tid + j * 256;
        float v = (j == 0 ? v0 : (j == 1 ? v1 : v2));
        float y = (v - mu) * rstd * g[col] + bb[col];
        if (out_bf) out_bf[(size_t)row * DD + col] = f2bf(y);
        if (out_f) out_f[(size_t)row * DD + col] = y;
    }
}

extern "C" void kernel_launch(void* const* d_in, const int* in_sizes, int n_in,
                              void* d_out, int out_size, void* d_ws, size_t ws_size,
                              hipStream_t stream) {
    const float* X    = (const float*)d_in[0];
    const int*   mask = (const int*)d_in[1];
    const float* Wq   = (const float*)d_in[2];
    const float* Wk   = (const float*)d_in[3];
    const float* Wv   = (const float*)d_in[4];
    const float* Wo   = (const float*)d_in[5];
    const float* W1   = (const float*)d_in[6];
    const float* W2   = (const float*)d_in[7];
    const float* ln_g = (const float*)d_in[8];
    const float* ln_b = (const float*)d_in[9];
    float* out = (float*)d_out;

    char* ws = (char*)d_ws;
    size_t off = 0;
    auto alloc = [&](size_t bytes) {
        void* p = ws + off;
        off += (bytes + 255) & ~(size_t)255;
        return p;
    };
    u16*   Xbf   = (u16*)alloc((size_t)ROWS * DD * 2);       // reused as Ctx
    u16*   Wqkvb = (u16*)alloc((size_t)3 * DD * DD * 2);
    u16*   Wob   = (u16*)alloc((size_t)DD * DD * 2);
    u16*   W1b   = (u16*)alloc((size_t)4 * DD * DD * 2);
    u16*   W2b   = (u16*)alloc((size_t)4 * DD * DD * 2);
    float* mbias = (float*)alloc((size_t)NB * SS * 4);
    u16*   Qb    = (u16*)alloc((size_t)ROWS * DD * 2);       // Qb..Vtb reused as Gb
    u16*   Kb    = (u16*)alloc((size_t)ROWS * DD * 2);
    u16*   Vb    = (u16*)alloc((size_t)ROWS * DD * 2);
    u16*   Vtb   = (u16*)alloc((size_t)ROWS * DD * 2);
    float* resid = (float*)alloc((size_t)ROWS * DD * 4);     // reused as h2
    u16*   n1b   = (u16*)alloc((size_t)ROWS * DD * 2);
    u16*   Gb    = Qb;          // 8192*3072*2 = 4 * (8192*768*2) = Qb..Vtb
    u16*   Ctxb  = Xbf;
    float* h2    = resid;

    // fused casts + mask bias (13064 blocks)
    prep_kernel<<<dim3(13064), dim3(256), 0, stream>>>(
        X, Wq, Wk, Wv, Wo, W1, W2, mask,
        Xbf, Wqkvb, Wob, W1b, W2b, mbias);

    // QKV projection: [8192, 2304], XCD-slab 1D grid
    gemm_bt<0, 128><<<dim3((3 * DD / 128) * (ROWS / 128)), dim3(256), 0, stream>>>(
        Xbf, Wqkvb, ROWS, 3 * DD, DD, nullptr, nullptr, Qb, Kb, Vb);

    transpose_v<<<dim3(SS / 32, HD / 32, NB * HH), dim3(256), 0, stream>>>(Vb, Vtb);

    // 1D XCD-swizzled grid: id = qb*48 + bh
    attn_kernel<<<dim3((SS / 128) * (NB * HH)), dim3(256), 0, stream>>>(
        Qb, Kb, Vtb, mbias, Ctxb);

    // O projection + residual: resid = x + ctx @ Wo^T
    gemm_bt<2, 64><<<dim3((DD / 64) * (ROWS / 128)), dim3(256), 0, stream>>>(
        Ctxb, Wob, ROWS, DD, DD, resid, X, nullptr, nullptr, nullptr);

    ln_kernel<<<dim3(ROWS), dim3(256), 0, stream>>>(resid, ln_g, ln_b, n1b, nullptr);

    // FFN1 + GELU(tanh-form): [8192, 3072] bf16
    gemm_bt<1, 128><<<dim3((4 * DD / 128) * (ROWS / 128)), dim3(256), 0, stream>>>(
        n1b, W1b, ROWS, 4 * DD, DD, Gb, nullptr, nullptr, nullptr, nullptr);

    // FFN2 + residual: h2 = n1 + g @ W2^T
    gemm_bt<3, 64><<<dim3((DD / 64) * (ROWS / 128)), dim3(256), 0, stream>>>(
        Gb, W2b, ROWS, DD, 4 * DD, h2, n1b, nullptr, nullptr, nullptr);

    ln_kernel<<<dim3(ROWS), dim3(256), 0, stream>>>(h2, ln_g, ln_b, nullptr, out);
}